// Round 10
// baseline (762.113 us; speedup 1.0000x reference)
//
#include <hip/hip_runtime.h>
#include <math.h>

namespace {
constexpr int B = 128;
constexpr int L = 4096;
constexpr int NBIN = 129;
constexpr int NFR = 33;

// workspace offsets (in floats), all multiples of 64
constexpr size_t F_MAG    = 0;                       // B*129*33 = 544896
constexpr size_t F_GW     = F_MAG + 544896;          // 256
constexpr size_t F_TOPI   = F_GW + 256;              // 256 (ints)
constexpr size_t F_EH1    = F_TOPI + 256;            // B*2*256*33 = 2162688
constexpr size_t F_SEL    = F_EH1 + 2162688;         // 2162688
constexpr size_t F_LINEF  = F_SEL + 2162688;         // B*256*64 = 2097152
constexpr size_t F_COMB   = F_LINEF + 2097152;       // 2162688 (bf16 [4224][512] uses half)
constexpr size_t F_XPROJ  = F_COMB + 2162688;        // 33*128*1024 = 4325376
constexpr size_t F_GATESB = F_XPROJ + 4325376;       // 128*1024 = 131072
constexpr size_t F_HF     = F_GATESB + 131072;       // 32768
constexpr size_t F_HBLAST = F_HF + 32768;            // 32768
constexpr size_t F_SESUM2 = F_HBLAST + 32768;        // 16384
constexpr size_t F_SESC2  = F_SESUM2 + 16384;        // 16384
constexpr size_t F_SESUM3 = F_SESC2 + 16384;         // 32768
constexpr size_t F_SESC3  = F_SESUM3 + 32768;        // 32768
constexpr size_t F_WHHB   = F_SESC3 + 32768;         // 131072 (bf16 whh, uint4 layout, 512KB)
constexpr size_t F_WKB    = F_WHHB + 131072;         // 20480 floats (128*320 bf16)
constexpr size_t F_WKB3   = F_WKB + 20480;           // 49152 floats (256*384 bf16)
constexpr size_t F_WIHF   = F_WKB3 + 49152;          // 262144 floats (1024*512 bf16)
constexpr size_t F_WIHB   = F_WIHF + 262144;         // 262144 floats
constexpr size_t F_BIGA   = F_WIHB + 262144;         // 8388608  (p1T bf16, later p2T bf16)
constexpr size_t F_BIGB   = F_BIGA + 8388608;        // 16777216 (h2, later h3)
}

typedef __attribute__((ext_vector_type(8))) short bf16x8;
typedef __attribute__((ext_vector_type(4))) float f32x4;

__device__ __forceinline__ float sigm(float x) { return 1.0f / (1.0f + expf(-x)); }

// fast saturating-safe gate functions (v_exp_f32 path)
__device__ __forceinline__ float fsigm(float x) { return 1.0f / (1.0f + __expf(-x)); }
__device__ __forceinline__ float ftanh(float x) { return 1.0f - 2.0f / (__expf(2.0f * x) + 1.0f); }

__device__ __forceinline__ unsigned int f2bf_rne(float f) {
    unsigned int u = __float_as_uint(f);
    return (u + 0x7FFFu + ((u >> 16) & 1u)) >> 16;
}

__device__ __forceinline__ float bflo(unsigned int u) { return __uint_as_float(u << 16); }
__device__ __forceinline__ float bfhi(unsigned int u) { return __uint_as_float(u & 0xFFFF0000u); }

// ---------------- STFT: per (b,frame) block, table DFT, 129 bins ----------------
__global__ __launch_bounds__(256) void stft_kernel(const float* __restrict__ x,
                                                   float* __restrict__ mag)
{
    int bf = blockIdx.x;            // b*33 + f
    int b = bf / NFR, f = bf % NFR;
    int tid = threadIdx.x;
    __shared__ float tbl[256];
    __shared__ float fx[256];
    tbl[tid] = cosf(6.28318530717958647692f * (float)tid / 256.0f);
    __syncthreads();
    {
        int j = f * 128 + tid - 128;
        if (j < 0) j = -j;
        else if (j >= L) j = 2 * L - 2 - j;
        float win = 0.5f * (1.0f - tbl[tid]);
        fx[tid] = x[(size_t)b * L + j] * win;
    }
    __syncthreads();
    if (tid < NBIN) {
        float re = 0.f, im = 0.f;
        int m = 0;
        for (int n = 0; n < 256; ++n) {
            float v = fx[n];
            re += v * tbl[m];
            im += v * tbl[(m + 192) & 255];
            m = (m + tid) & 255;
        }
        mag[((size_t)b * NBIN + tid) * NFR + f] = sqrtf(re * re + im * im);
    }
}

// ---------------- pooled mean + gate MLP + top2 ----------------
__global__ __launch_bounds__(128) void gate_kernel(const float* __restrict__ mag,
                                                   const float* __restrict__ w1,
                                                   const float* __restrict__ b1,
                                                   const float* __restrict__ w2,
                                                   const float* __restrict__ b2,
                                                   int* __restrict__ topi,
                                                   float* __restrict__ gw)
{
    int b = blockIdx.x, tid = threadIdx.x;
    __shared__ float pooled[NBIN];
    __shared__ float h1[128];
    __shared__ float lg[8];
    for (int k = tid; k < NBIN; k += 128) {
        const float* mp = mag + ((size_t)b * NBIN + k) * NFR;
        float s = 0.f;
        for (int f = 0; f < NFR; ++f) s += mp[f];
        pooled[k] = s * (1.0f / 33.0f);
    }
    __syncthreads();
    {
        float acc = b1[tid];
        const float* wr = w1 + tid * NBIN;
        for (int k = 0; k < NBIN; ++k) acc += pooled[k] * wr[k];
        h1[tid] = fmaxf(acc, 0.f);
    }
    __syncthreads();
    if (tid < 8) {
        float a = b2[tid];
        const float* w = w2 + tid * 128;
        for (int j = 0; j < 128; ++j) a += h1[j] * w[j];
        lg[tid] = a;
    }
    __syncthreads();
    if (tid == 0) {
        int i0 = 0; float v0 = lg[0];
        for (int e = 1; e < 8; ++e) if (lg[e] > v0) { v0 = lg[e]; i0 = e; }
        int i1 = -1; float v1 = -3.0e38f;
        for (int e = 0; e < 8; ++e) { if (e == i0) continue; if (lg[e] > v1) { v1 = lg[e]; i1 = e; } }
        float m = fmaxf(v0, v1);
        float e0 = expf(v0 - m), e1 = expf(v1 - m);
        float inv = 1.0f / (e0 + e1);
        topi[b * 2 + 0] = i0; topi[b * 2 + 1] = i1;
        gw[b * 2 + 0] = e0 * inv; gw[b * 2 + 1] = e1 * inv;
    }
}

// ---------------- expert conv1: 129ch -> 256ch, k=5, pad=2, len 33 ----------------
__global__ __launch_bounds__(512) void expert_conv1_kernel(const float* __restrict__ mag,
                                                           const int* __restrict__ topi,
                                                           const float* __restrict__ W,
                                                           const float* __restrict__ Bb,
                                                           float* __restrict__ out)
{
    int b = blockIdx.x, slot = blockIdx.y;
    int e = topi[b * 2 + slot];
    __shared__ float sm[129 * 37 + 16];
    int tid = threadIdx.x;
    for (int i = tid; i < 129 * 37 + 16; i += 512) sm[i] = 0.f;
    __syncthreads();
    for (int i = tid; i < 129 * 33; i += 512) {
        int ic = i / 33, t = i % 33;
        sm[ic * 37 + 2 + t] = mag[((size_t)b * NBIN + ic) * NFR + t];
    }
    __syncthreads();
    int oc = (blockIdx.z << 7) + (tid >> 2);
    int tq = tid & 3;
    int t0 = tq * 9;
    int nt = (tq == 3) ? 6 : 9;
    float acc[9];
#pragma unroll
    for (int i = 0; i < 9; ++i) acc[i] = 0.f;
    const float* wp = W + ((size_t)e * 256 + oc) * (129 * 5);
    for (int ic = 0; ic < 129; ++ic) {
        const float* wr = wp + ic * 5;
        const float* sr = sm + ic * 37 + t0;
        float w0 = wr[0], w1 = wr[1], w2 = wr[2], w3 = wr[3], w4 = wr[4];
#pragma unroll
        for (int t = 0; t < 9; ++t)
            acc[t] += w0 * sr[t] + w1 * sr[t + 1] + w2 * sr[t + 2] + w3 * sr[t + 3] + w4 * sr[t + 4];
    }
    float bias = Bb[e * 256 + oc];
    float* op = out + (((size_t)b * 2 + slot) * 256 + oc) * NFR + t0;
    for (int t = 0; t < nt; ++t) op[t] = fmaxf(acc[t] + bias, 0.f);
}

// ---------------- expert conv2: 256ch -> 256ch, k=3, pad=1, len 33 ----------------
__global__ __launch_bounds__(512) void expert_conv2_kernel(const float* __restrict__ eh1,
                                                           const int* __restrict__ topi,
                                                           const float* __restrict__ W,
                                                           const float* __restrict__ Bb,
                                                           float* __restrict__ out)
{
    int b = blockIdx.x, slot = blockIdx.y;
    int e = topi[b * 2 + slot];
    __shared__ float sm[256 * 37 + 16];
    int tid = threadIdx.x;
    for (int i = tid; i < 256 * 37 + 16; i += 512) sm[i] = 0.f;
    __syncthreads();
    for (int i = tid; i < 256 * 33; i += 512) {
        int ic = i / 33, t = i % 33;
        sm[ic * 37 + 2 + t] = eh1[(((size_t)b * 2 + slot) * 256 + ic) * NFR + t];
    }
    __syncthreads();
    int oc = (blockIdx.z << 7) + (tid >> 2);
    int tq = tid & 3;
    int t0 = tq * 9;
    int nt = (tq == 3) ? 6 : 9;
    float acc[9];
#pragma unroll
    for (int i = 0; i < 9; ++i) acc[i] = 0.f;
    const float* wp = W + ((size_t)e * 256 + oc) * (256 * 3);
    for (int ic = 0; ic < 256; ++ic) {
        const float* wr = wp + ic * 3;
        const float* sr = sm + ic * 37 + t0;
        float w0 = wr[0], w1 = wr[1], w2 = wr[2];
#pragma unroll
        for (int t = 0; t < 9; ++t)
            acc[t] += w0 * sr[t + 1] + w1 * sr[t + 2] + w2 * sr[t + 3];
    }
    float bias = Bb[e * 256 + oc];
    float* op = out + (((size_t)b * 2 + slot) * 256 + oc) * NFR + t0;
    for (int t = 0; t < nt; ++t) op[t] = fmaxf(acc[t] + bias, 0.f);
}

// ---------------- line conv1 (1->64, k7, pad3) + relu + maxpool4 -> p1T bf16 [b][t][ic] ----------------
__global__ __launch_bounds__(256) void line1_kernel(const float* __restrict__ x,
                                                    const float* __restrict__ lw1,
                                                    const float* __restrict__ lb1,
                                                    unsigned short* __restrict__ p1T)
{
    int b = blockIdx.x;
    int P0 = blockIdx.y * 256;
    __shared__ float sx[1032];
    __shared__ float w[448];
    __shared__ float bb[64];
    __shared__ unsigned short sT[256 * 65];
    int tid = threadIdx.x;
    for (int i = tid; i < 448; i += 256) w[i] = lw1[i];
    for (int i = tid; i < 64; i += 256) bb[i] = lb1[i];
    int base = 4 * P0 - 3;
    for (int i = tid; i < 1032; i += 256) {
        int g = base + i;
        sx[i] = (g >= 0 && g < L) ? x[(size_t)b * L + g] : 0.f;
    }
    __syncthreads();
    int p = tid;
    for (int oc = 0; oc < 64; ++oc) {
        const float* wr = w + oc * 7;
        float best = -3.0e38f;
#pragma unroll
        for (int q = 0; q < 4; ++q) {
            const float* s = sx + 4 * p + q;
            float v = wr[0]*s[0] + wr[1]*s[1] + wr[2]*s[2] + wr[3]*s[3] + wr[4]*s[4] + wr[5]*s[5] + wr[6]*s[6];
            best = fmaxf(best, v);
        }
        float v = fmaxf(best + bb[oc], 0.f);
        sT[p * 65 + oc] = (unsigned short)f2bf_rne(v);
    }
    __syncthreads();
    unsigned int* outw = reinterpret_cast<unsigned int*>(p1T);
    for (int i2 = tid; i2 < 256 * 32; i2 += 256) {
        int row = i2 >> 5, dw = i2 & 31;
        unsigned int lo = sT[row * 65 + dw * 2];
        unsigned int hi = sT[row * 65 + dw * 2 + 1];
        outw[((size_t)b * 1024 + P0 + row) * 32 + dw] = lo | (hi << 16);
    }
}

// ---------------- prep line2 weights: lw2[oc][ic][k] f32 -> wkb[oc][K'=k*64+ic] bf16 ----------------
__global__ __launch_bounds__(256) void prep_wkb_kernel(const float* __restrict__ W,
                                                       unsigned short* __restrict__ wkb)
{
    int idx = blockIdx.x * 256 + threadIdx.x;   // 128*320
    if (idx >= 128 * 320) return;
    int oc = idx / 320, K = idx % 320;
    int k = K >> 6, ic = K & 63;
    wkb[idx] = (unsigned short)f2bf_rne(W[oc * 320 + ic * 5 + k]);
}

// ---------------- line conv2 via MFMA: C[128 oc][1024 t] = W[128][320] x im2col ----------------
__global__ __launch_bounds__(256) void line2_mfma_kernel(const unsigned short* __restrict__ p1T,
                                                         const unsigned short* __restrict__ wkb,
                                                         const float* __restrict__ lb2,
                                                         float* __restrict__ h2,
                                                         float* __restrict__ seSum2)
{
    int b = blockIdx.x;
    int t0 = blockIdx.y * 128;
    __shared__ __align__(16) unsigned short wl[128 * 320];   // 80 KB, XOR-swizzled 16B chunks
    __shared__ __align__(16) unsigned short inT[132 * 64];   // 16.9 KB, rows j=t_rel+2, XOR-swizzled
    __shared__ float bias[128];
    int tid = threadIdx.x;

    for (int idx = tid; idx < 128 * 40; idx += 256) {
        int oc = idx / 40, ch = idx % 40;
        int swz = (ch & ~7) | ((ch & 7) ^ (oc & 7));
        *reinterpret_cast<uint4*>(&wl[oc * 320 + swz * 8]) =
            *reinterpret_cast<const uint4*>(&wkb[oc * 320 + ch * 8]);
    }
    for (int idx = tid; idx < 132 * 8; idx += 256) {
        int j = idx / 8, ch = idx % 8;
        int t = t0 - 2 + j;
        uint4 v = make_uint4(0u, 0u, 0u, 0u);
        if (t >= 0 && t < 1024)
            v = *reinterpret_cast<const uint4*>(&p1T[((size_t)b * 1024 + t) * 64 + ch * 8]);
        int swz = ch ^ (j & 7);
        *reinterpret_cast<uint4*>(&inT[j * 64 + swz * 8]) = v;
    }
    if (tid < 128) bias[tid] = lb2[tid];
    __syncthreads();

    int lane = tid & 63;
    int w = tid >> 6;
    int l15 = lane & 15, g = lane >> 4;

    f32x4 acc[8][2];
#pragma unroll
    for (int ot = 0; ot < 8; ++ot) {
        acc[ot][0] = (f32x4){0.f, 0.f, 0.f, 0.f};
        acc[ot][1] = (f32x4){0.f, 0.f, 0.f, 0.f};
    }

    for (int ks = 0; ks < 10; ++ks) {
        int k = ks >> 1;
        bf16x8 bf0, bf1;
        {
            int j = w * 32 + l15 + k;
            int ch = (ks & 1) * 4 + g;
            bf0 = *reinterpret_cast<const bf16x8*>(&inT[j * 64 + (ch ^ (j & 7)) * 8]);
            int j1 = j + 16;
            bf1 = *reinterpret_cast<const bf16x8*>(&inT[j1 * 64 + (ch ^ (j1 & 7)) * 8]);
        }
#pragma unroll
        for (int ot = 0; ot < 8; ++ot) {
            int row = ot * 16 + l15;
            int ch = ks * 4 + g;
            int swz = (ch & ~7) | ((ch & 7) ^ (row & 7));
            bf16x8 af = *reinterpret_cast<const bf16x8*>(&wl[row * 320 + swz * 8]);
            acc[ot][0] = __builtin_amdgcn_mfma_f32_16x16x32_bf16(af, bf0, acc[ot][0], 0, 0, 0);
            acc[ot][1] = __builtin_amdgcn_mfma_f32_16x16x32_bf16(af, bf1, acc[ot][1], 0, 0, 0);
        }
    }

    int tcol = t0 + w * 32 + l15;
#pragma unroll
    for (int ot = 0; ot < 8; ++ot) {
#pragma unroll
        for (int r = 0; r < 4; ++r) {
            int oc = ot * 16 + g * 4 + r;
            float bv = bias[oc];
            float v0 = fmaxf(acc[ot][0][r] + bv, 0.f);
            float v1 = fmaxf(acc[ot][1][r] + bv, 0.f);
            float* hp = h2 + ((size_t)b * 128 + oc) * 1024 + tcol;
            hp[0] = v0;
            hp[16] = v1;
            float s = v0 + v1;
            s += __shfl_xor(s, 1);
            s += __shfl_xor(s, 2);
            s += __shfl_xor(s, 4);
            s += __shfl_xor(s, 8);
            if (l15 == 0) atomicAdd(&seSum2[b * 128 + oc], s);
        }
    }
}

// ---------------- SE for stage2 ----------------
__global__ __launch_bounds__(128) void se2_kernel(const float* __restrict__ seSum2,
                                                  const float* __restrict__ w1,
                                                  const float* __restrict__ w2,
                                                  float* __restrict__ seScale2)
{
    int b = blockIdx.x, tid = threadIdx.x;
    __shared__ float y[128];
    __shared__ float z[32];
    y[tid] = seSum2[b * 128 + tid] * (1.0f / 1024.0f);
    __syncthreads();
    if (tid < 32) {
        float a = 0.f;
        const float* wr = w1 + tid * 128;
        for (int c = 0; c < 128; ++c) a += y[c] * wr[c];
        z[tid] = fmaxf(a, 0.f);
    }
    __syncthreads();
    {
        float a = 0.f;
        const float* wr = w2 + tid * 32;
        for (int j = 0; j < 32; ++j) a += z[j] * wr[j];
        seScale2[b * 128 + tid] = sigm(a);
    }
}

// ---------------- pool2 + transpose: p2T bf16 [b][p][ic] = scale*maxpool4(h2) ----------------
__global__ __launch_bounds__(256) void pool2t_kernel(const float* __restrict__ h2,
                                                     const float* __restrict__ seScale2,
                                                     unsigned short* __restrict__ p2T)
{
    int b = blockIdx.x, p = threadIdx.x;   // p in [0,256)
    __shared__ unsigned short sT[256 * 129];
    for (int c = 0; c < 128; ++c) {
        float4 v = *reinterpret_cast<const float4*>(&h2[((size_t)b * 128 + c) * 1024 + 4 * p]);
        float m = fmaxf(fmaxf(v.x, v.y), fmaxf(v.z, v.w)) * seScale2[b * 128 + c];
        sT[p * 129 + c] = (unsigned short)f2bf_rne(m);
    }
    __syncthreads();
    unsigned int* out = reinterpret_cast<unsigned int*>(p2T);
    for (int idx = p; idx < 256 * 64; idx += 256) {
        int row = idx >> 6, dw = idx & 63;
        unsigned int lo = sT[row * 129 + dw * 2];
        unsigned int hi = sT[row * 129 + dw * 2 + 1];
        out[((size_t)b * 256 + row) * 64 + dw] = lo | (hi << 16);
    }
}

// ---------------- prep line3 weights: lw3[oc][ic][k] f32 -> wkb3[oc][K'=k*128+ic] bf16 ----------------
__global__ __launch_bounds__(256) void prep_wkb3_kernel(const float* __restrict__ W,
                                                        unsigned short* __restrict__ wkb3)
{
    int idx = blockIdx.x * 256 + threadIdx.x;   // 256*384
    if (idx >= 256 * 384) return;
    int oc = idx / 384, K = idx % 384;
    int k = K >> 7, ic = K & 127;
    wkb3[idx] = (unsigned short)f2bf_rne(W[oc * 384 + ic * 3 + k]);
}

// ---------------- line conv3 via MFMA: per block 128oc x 128t, K'=384 ----------------
__global__ __launch_bounds__(256) void line3_mfma_kernel(const unsigned short* __restrict__ p2T,
                                                         const unsigned short* __restrict__ wkb3,
                                                         const float* __restrict__ lb3,
                                                         float* __restrict__ h3,
                                                         float* __restrict__ seSum3)
{
    int b = blockIdx.x;
    int oc0 = blockIdx.y * 128;
    int t0 = blockIdx.z * 128;
    __shared__ __align__(16) unsigned short wl[128 * 384];   // 96 KB
    __shared__ __align__(16) unsigned short inT[130 * 128];  // 32.5 KB
    __shared__ float bias[128];
    int tid = threadIdx.x;

    for (int idx = tid; idx < 128 * 48; idx += 256) {
        int oc = idx / 48, ch = idx % 48;
        int swz = (ch & ~7) | ((ch & 7) ^ (oc & 7));
        *reinterpret_cast<uint4*>(&wl[oc * 384 + swz * 8]) =
            *reinterpret_cast<const uint4*>(&wkb3[(size_t)(oc0 + oc) * 384 + ch * 8]);
    }
    for (int idx = tid; idx < 130 * 16; idx += 256) {
        int j = idx / 16, ch = idx % 16;
        int t = t0 - 1 + j;
        uint4 v = make_uint4(0u, 0u, 0u, 0u);
        if (t >= 0 && t < 256)
            v = *reinterpret_cast<const uint4*>(&p2T[((size_t)b * 256 + t) * 128 + ch * 8]);
        int swz = ch ^ (j & 15);
        *reinterpret_cast<uint4*>(&inT[j * 128 + swz * 8]) = v;
    }
    if (tid < 128) bias[tid] = lb3[oc0 + tid];
    __syncthreads();

    int lane = tid & 63;
    int w = tid >> 6;
    int l15 = lane & 15, g = lane >> 4;

    f32x4 acc[8][2];
#pragma unroll
    for (int ot = 0; ot < 8; ++ot) {
        acc[ot][0] = (f32x4){0.f, 0.f, 0.f, 0.f};
        acc[ot][1] = (f32x4){0.f, 0.f, 0.f, 0.f};
    }

    for (int ks = 0; ks < 12; ++ks) {
        int k = ks >> 2;                 // tap
        int ch = (ks & 3) * 4 + g;       // ic chunk within row
        bf16x8 bf0, bf1;
        {
            int j = w * 32 + l15 + k;
            bf0 = *reinterpret_cast<const bf16x8*>(&inT[j * 128 + (ch ^ (j & 15)) * 8]);
            int j1 = j + 16;
            bf1 = *reinterpret_cast<const bf16x8*>(&inT[j1 * 128 + (ch ^ (j1 & 15)) * 8]);
        }
#pragma unroll
        for (int ot = 0; ot < 8; ++ot) {
            int row = ot * 16 + l15;
            int wch = ks * 4 + g;
            int swz = (wch & ~7) | ((wch & 7) ^ (row & 7));
            bf16x8 af = *reinterpret_cast<const bf16x8*>(&wl[row * 384 + swz * 8]);
            acc[ot][0] = __builtin_amdgcn_mfma_f32_16x16x32_bf16(af, bf0, acc[ot][0], 0, 0, 0);
            acc[ot][1] = __builtin_amdgcn_mfma_f32_16x16x32_bf16(af, bf1, acc[ot][1], 0, 0, 0);
        }
    }

    int tcol = t0 + w * 32 + l15;
#pragma unroll
    for (int ot = 0; ot < 8; ++ot) {
#pragma unroll
        for (int r = 0; r < 4; ++r) {
            int ocl = ot * 16 + g * 4 + r;
            int oc = oc0 + ocl;
            float bv = bias[ocl];
            float v0 = fmaxf(acc[ot][0][r] + bv, 0.f);
            float v1 = fmaxf(acc[ot][1][r] + bv, 0.f);
            float* hp = h3 + ((size_t)b * 256 + oc) * 256 + tcol;
            hp[0] = v0;
            hp[16] = v1;
            float s = v0 + v1;
            s += __shfl_xor(s, 1);
            s += __shfl_xor(s, 2);
            s += __shfl_xor(s, 4);
            s += __shfl_xor(s, 8);
            if (l15 == 0) atomicAdd(&seSum3[b * 256 + oc], s);
        }
    }
}

// ---------------- SE for stage3 ----------------
__global__ __launch_bounds__(256) void se3_kernel(const float* __restrict__ seSum3,
                                                  const float* __restrict__ w1,
                                                  const float* __restrict__ w2,
                                                  float* __restrict__ seScale3)
{
    int b = blockIdx.x, tid = threadIdx.x;
    __shared__ float y[256];
    __shared__ float z[64];
    y[tid] = seSum3[b * 256 + tid] * (1.0f / 256.0f);
    __syncthreads();
    if (tid < 64) {
        float a = 0.f;
        const float* wr = w1 + tid * 256;
        for (int c = 0; c < 256; ++c) a += y[c] * wr[c];
        z[tid] = fmaxf(a, 0.f);
    }
    __syncthreads();
    {
        float a = 0.f;
        const float* wr = w2 + tid * 64;
        for (int j = 0; j < 64; ++j) a += z[j] * wr[j];
        seScale3[b * 256 + tid] = sigm(a);
    }
}

// ---------------- pool stage3: lineFeat = scale * maxpool4(h3) ----------------
__global__ __launch_bounds__(256) void pool3_kernel(const float* __restrict__ h3,
                                                    const float* __restrict__ seScale3,
                                                    float* __restrict__ lineFeat)
{
    const int total = 128 * 256 * 64;
    for (int idx = blockIdx.x * 256 + threadIdx.x; idx < total; idx += gridDim.x * 256) {
        int b = idx >> 14;
        int c = (idx >> 6) & 255;
        int p = idx & 63;
        const float* hp = h3 + (((size_t)b * 256 + c) * 256) + 4 * p;
        float v = fmaxf(fmaxf(hp[0], hp[1]), fmaxf(hp[2], hp[3]));
        lineFeat[idx] = v * seScale3[b * 256 + c];
    }
}

// ---------------- build comb bf16 (33*128, 512): freq combine + line interp ----------------
__global__ __launch_bounds__(256) void comb_kernel(const float* __restrict__ sel,
                                                   const float* __restrict__ gw,
                                                   const float* __restrict__ lineFeat,
                                                   unsigned short* __restrict__ combB)
{
    const int total = 33 * 128 * 512;
    for (int idx = blockIdx.x * 256 + threadIdx.x; idx < total; idx += gridDim.x * 256) {
        int c = idx & 511;
        int r = idx >> 9;         // t*128 + b
        int b = r & 127;
        int t = r >> 7;
        float v;
        if (c < 256) {
            float g0 = gw[b * 2 + 0], g1 = gw[b * 2 + 1];
            v = g0 * sel[(((size_t)b * 2 + 0) * 256 + c) * NFR + t]
              + g1 * sel[(((size_t)b * 2 + 1) * 256 + c) * NFR + t];
        } else {
            int cc = c - 256;
            float xc = ((float)t + 0.5f) * (64.0f / 33.0f) - 0.5f;
            xc = fminf(fmaxf(xc, 0.0f), 63.0f);
            int lo = (int)floorf(xc);
            int hi = lo + 1; if (hi > 63) hi = 63;
            float w = xc - (float)lo;
            const float* lp = lineFeat + ((size_t)b * 256 + cc) * 64;
            v = lp[lo] * (1.0f - w) + lp[hi] * w;
        }
        combB[idx] = (unsigned short)f2bf_rne(v);
    }
}

// ---------------- generic f32 -> bf16 pack (n multiple of 4) ----------------
__global__ __launch_bounds__(256) void pack_bf16_kernel(const float* __restrict__ in,
                                                        unsigned short* __restrict__ out,
                                                        int n)
{
    int i = (blockIdx.x * 256 + threadIdx.x) * 4;
    if (i >= n) return;
    float4 v = *reinterpret_cast<const float4*>(in + i);
    uint2 w;
    w.x = f2bf_rne(v.x) | (f2bf_rne(v.y) << 16);
    w.y = f2bf_rne(v.z) | (f2bf_rne(v.w) << 16);
    *reinterpret_cast<uint2*>(out + i) = w;
}

// ---------------- MFMA GEMM: out[M][1024] = A[M][512]bf16 x W[1024][512]^T bf16 + b1 + b2 ----
// grid (M/128, 8). 256 thr / 4 waves. Fragment pattern = line3_mfma (verified).
__global__ __launch_bounds__(256) void gemm_mfma_kernel(const unsigned short* __restrict__ A,
                                                        const unsigned short* __restrict__ W,
                                                        const float* __restrict__ b1,
                                                        const float* __restrict__ b2,
                                                        float* __restrict__ out)
{
    int row0 = blockIdx.x * 128;
    int col0 = blockIdx.y * 128;
    __shared__ __align__(16) unsigned short As[128 * 64];
    __shared__ __align__(16) unsigned short Bs[128 * 64];
    __shared__ float bias[128];
    int tid = threadIdx.x;
    if (tid < 128) bias[tid] = b1[col0 + tid] + b2[col0 + tid];
    int lane = tid & 63, w = tid >> 6, l15 = lane & 15, g = lane >> 4;

    f32x4 acc[8][2];
#pragma unroll
    for (int ot = 0; ot < 8; ++ot) {
        acc[ot][0] = (f32x4){0.f, 0.f, 0.f, 0.f};
        acc[ot][1] = (f32x4){0.f, 0.f, 0.f, 0.f};
    }

    for (int kc = 0; kc < 8; ++kc) {
        __syncthreads();
        for (int idx = tid; idx < 1024; idx += 256) {
            int r = idx >> 3, ch = idx & 7;
            int swz = ch ^ (r & 7);
            *reinterpret_cast<uint4*>(&As[r * 64 + swz * 8]) =
                *reinterpret_cast<const uint4*>(&A[(size_t)(row0 + r) * 512 + kc * 64 + ch * 8]);
            *reinterpret_cast<uint4*>(&Bs[r * 64 + swz * 8]) =
                *reinterpret_cast<const uint4*>(&W[(size_t)(col0 + r) * 512 + kc * 64 + ch * 8]);
        }
        __syncthreads();
#pragma unroll
        for (int ks = 0; ks < 2; ++ks) {
            int ch = ks * 4 + g;
            int j = w * 32 + l15;
            bf16x8 bf0 = *reinterpret_cast<const bf16x8*>(&As[j * 64 + (ch ^ (j & 7)) * 8]);
            int j1 = j + 16;
            bf16x8 bf1 = *reinterpret_cast<const bf16x8*>(&As[j1 * 64 + (ch ^ (j1 & 7)) * 8]);
#pragma unroll
            for (int ot = 0; ot < 8; ++ot) {
                int row = ot * 16 + l15;
                bf16x8 af = *reinterpret_cast<const bf16x8*>(&Bs[row * 64 + (ch ^ (row & 7)) * 8]);
                acc[ot][0] = __builtin_amdgcn_mfma_f32_16x16x32_bf16(af, bf0, acc[ot][0], 0, 0, 0);
                acc[ot][1] = __builtin_amdgcn_mfma_f32_16x16x32_bf16(af, bf1, acc[ot][1], 0, 0, 0);
            }
        }
    }

    int rbase = row0 + w * 32 + l15;
#pragma unroll
    for (int ot = 0; ot < 8; ++ot) {
#pragma unroll
        for (int r = 0; r < 4; ++r) {
            int ocl = ot * 16 + g * 4 + r;
            float bv = bias[ocl];
            out[(size_t)rbase * 1024 + col0 + ocl] = acc[ot][0][r] + bv;
            out[(size_t)(rbase + 16) * 1024 + col0 + ocl] = acc[ot][1][r] + bv;
        }
    }
}

// ---------------- pack whh_f (1024,256) -> bf16 whh4: uint4[k8*1024 + j] ----------------
__global__ __launch_bounds__(256) void prep_whh4_kernel(const float* __restrict__ W,
                                                        uint4* __restrict__ whh4)
{
    int idx = blockIdx.x * 256 + threadIdx.x;   // 32768 (k8, j) pairs
    int k8 = idx >> 10, j = idx & 1023;
    const float* src = W + (size_t)j * 256 + k8 * 8;
    float4 v0 = *reinterpret_cast<const float4*>(src);
    float4 v1 = *reinterpret_cast<const float4*>(src + 4);
    uint4 w;
    w.x = f2bf_rne(v0.x) | (f2bf_rne(v0.y) << 16);
    w.y = f2bf_rne(v0.z) | (f2bf_rne(v0.w) << 16);
    w.z = f2bf_rne(v1.x) | (f2bf_rne(v1.y) << 16);
    w.w = f2bf_rne(v1.z) | (f2bf_rne(v1.w) << 16);
    whh4[(size_t)k8 * 1024 + j] = w;
}

// ---------------- fused forward LSTM: 2 batches per block, 8 weight slices in LDS --------
// 64 blocks x 1024 threads. Per-CU L2 weight stream cut 512KB->384KB/step (8 of 32 k8
// slices staged once in LDS, 128KB) and amortized over 2 batches. NO register-resident
// weights (R7/R8: hipcc caps 1024-thr kernels at 64 VGPR; wreg spills -> 1GB scratch).
__global__ __launch_bounds__(1024) void lstm_fused_kernel(const float* __restrict__ xproj,
                                                          const uint4* __restrict__ whh4,
                                                          float* __restrict__ hfinal)
{
    int b0 = blockIdx.x * 2;
    int j = threadIdx.x;
    __shared__ __align__(16) float h[2][256];
    __shared__ float cc[2][256];
    __shared__ float g[2][1024];
    __shared__ __align__(16) uint4 wlds[8 * 1024];   // 128 KB
    const uint4* wp = whh4 + j;
    for (int s = 0; s < 8; ++s) wlds[s * 1024 + j] = wp[s << 10];
    if (j < 512) { h[j >> 8][j & 255] = 0.f; cc[j >> 8][j & 255] = 0.f; }
    __syncthreads();
    const uint4* wg = wp + ((size_t)8 << 10);
    for (int t = 0; t < 33; ++t) {
        float xa = xproj[(size_t)t * 131072 + (size_t)b0 * 1024 + j];
        float xb = xproj[(size_t)t * 131072 + (size_t)(b0 + 1) * 1024 + j];
        float a0 = 0.f, a1 = 0.f, a2 = 0.f, a3 = 0.f;
#pragma unroll
        for (int s = 0; s < 8; ++s) {
            uint4 w = wlds[s * 1024 + j];
            float4 ha0 = *reinterpret_cast<const float4*>(&h[0][s * 8]);
            float4 ha1 = *reinterpret_cast<const float4*>(&h[0][s * 8 + 4]);
            float4 hb0 = *reinterpret_cast<const float4*>(&h[1][s * 8]);
            float4 hb1 = *reinterpret_cast<const float4*>(&h[1][s * 8 + 4]);
            a0 += bflo(w.x) * ha0.x + bfhi(w.x) * ha0.y + bflo(w.y) * ha0.z + bfhi(w.y) * ha0.w;
            a1 += bflo(w.z) * ha1.x + bfhi(w.z) * ha1.y + bflo(w.w) * ha1.z + bfhi(w.w) * ha1.w;
            a2 += bflo(w.x) * hb0.x + bfhi(w.x) * hb0.y + bflo(w.y) * hb0.z + bfhi(w.y) * hb0.w;
            a3 += bflo(w.z) * hb1.x + bfhi(w.z) * hb1.y + bflo(w.w) * hb1.z + bfhi(w.w) * hb1.w;
        }
#pragma unroll 6
        for (int k8 = 8; k8 < 32; ++k8) {
            uint4 w = wg[(k8 - 8) << 10];
            float4 ha0 = *reinterpret_cast<const float4*>(&h[0][k8 * 8]);
            float4 ha1 = *reinterpret_cast<const float4*>(&h[0][k8 * 8 + 4]);
            float4 hb0 = *reinterpret_cast<const float4*>(&h[1][k8 * 8]);
            float4 hb1 = *reinterpret_cast<const float4*>(&h[1][k8 * 8 + 4]);
            a0 += bflo(w.x) * ha0.x + bfhi(w.x) * ha0.y + bflo(w.y) * ha0.z + bfhi(w.y) * ha0.w;
            a1 += bflo(w.z) * ha1.x + bfhi(w.z) * ha1.y + bflo(w.w) * ha1.z + bfhi(w.w) * ha1.w;
            a2 += bflo(w.x) * hb0.x + bfhi(w.x) * hb0.y + bflo(w.y) * hb0.z + bfhi(w.y) * hb0.w;
            a3 += bflo(w.z) * hb1.x + bfhi(w.z) * hb1.y + bflo(w.w) * hb1.z + bfhi(w.w) * hb1.w;
        }
        g[0][j] = xa + a0 + a1;
        g[1][j] = xb + a2 + a3;
        __syncthreads();
        if (j < 512) {
            int jb = j >> 8, u = j & 255;
            float gi = g[jb][u], gf = g[jb][256 + u], gz = g[jb][512 + u], go = g[jb][768 + u];
            float c = fsigm(gf) * cc[jb][u] + fsigm(gi) * ftanh(gz);
            cc[jb][u] = c;
            h[jb][u] = fsigm(go) * ftanh(c);
        }
        __syncthreads();
    }
    if (j < 512) hfinal[(size_t)(b0 + (j >> 8)) * 256 + (j & 255)] = h[j >> 8][j & 255];
}

// ---------------- backward LSTM single step from zero state ----------------
__global__ __launch_bounds__(256) void lstm_bwd_tail_kernel(const float* __restrict__ gatesB,
                                                            float* __restrict__ hbLast)
{
    int b = blockIdx.x, u = threadIdx.x;
    const float* g = gatesB + (size_t)b * 1024;
    float ai = g[u], ag = g[512 + u], ao = g[768 + u];
    float c = sigm(ai) * tanhf(ag);
    hbLast[b * 256 + u] = sigm(ao) * tanhf(c);
}

// ---------------- FFN head ----------------
__global__ __launch_bounds__(256) void ffn_kernel(const float* __restrict__ hf,
                                                  const float* __restrict__ hb,
                                                  const float* __restrict__ w1,
                                                  const float* __restrict__ b1,
                                                  const float* __restrict__ w2,
                                                  const float* __restrict__ b2,
                                                  float* __restrict__ out)
{
    int b = blockIdx.x, tid = threadIdx.x;
    __shared__ float last[512];
    __shared__ float red[256];
    last[tid] = hf[b * 256 + tid];
    last[256 + tid] = hb[b * 256 + tid];
    __syncthreads();
    float a = b1[tid];
    const float* wr = w1 + (size_t)tid * 512;
    for (int k = 0; k < 512; ++k) a += last[k] * wr[k];
    red[tid] = fmaxf(a, 0.f) * w2[tid];
    __syncthreads();
    for (int s = 128; s > 0; s >>= 1) {
        if (tid < s) red[tid] += red[tid + s];
        __syncthreads();
    }
    if (tid == 0) out[b] = red[0] + b2[0];
}

extern "C" void kernel_launch(void* const* d_in, const int* in_sizes, int n_in,
                              void* d_out, int out_size, void* d_ws, size_t ws_size,
                              hipStream_t stream)
{
    (void)in_sizes; (void)n_in; (void)out_size; (void)ws_size;
    const float* x_cont = (const float*)d_in[0];
    const float* x_norm = (const float*)d_in[1];
    const float* gate_w1 = (const float*)d_in[2];
    const float* gate_b1 = (const float*)d_in[3];
    const float* gate_w2 = (const float*)d_in[4];
    const float* gate_b2 = (const float*)d_in[5];
    const float* exp_w1 = (const float*)d_in[6];
    const float* exp_b1 = (const float*)d_in[7];
    const float* exp_w2 = (const float*)d_in[8];
    const float* exp_b2 = (const float*)d_in[9];
    const float* lw1 = (const float*)d_in[10];
    const float* lb1 = (const float*)d_in[11];
    const float* lw2 = (const float*)d_in[12];
    const float* lb2 = (const float*)d_in[13];
    const float* se2_w1 = (const float*)d_in[14];
    const float* se2_w2 = (const float*)d_in[15];
    const float* lw3 = (const float*)d_in[16];
    const float* lb3 = (const float*)d_in[17];
    const float* se3_w1 = (const float*)d_in[18];
    const float* se3_w2 = (const float*)d_in[19];
    const float* wih_f = (const float*)d_in[20];
    const float* whh_f = (const float*)d_in[21];
    const float* bih_f = (const float*)d_in[22];
    const float* bhh_f = (const float*)d_in[23];
    const float* wih_b = (const float*)d_in[24];
    const float* whh_b = (const float*)d_in[25];
    const float* bih_b = (const float*)d_in[26];
    const float* bhh_b = (const float*)d_in[27];
    const float* ffn_w1 = (const float*)d_in[28];
    const float* ffn_b1 = (const float*)d_in[29];
    const float* ffn_w2 = (const float*)d_in[30];
    const float* ffn_b2 = (const float*)d_in[31];

    float* ws = (float*)d_ws;
    float* mag     = ws + F_MAG;
    float* gw      = ws + F_GW;
    int*   topi    = (int*)(ws + F_TOPI);
    float* eh1     = ws + F_EH1;
    float* sel     = ws + F_SEL;
    float* lineFeat= ws + F_LINEF;
    unsigned short* combB = (unsigned short*)(ws + F_COMB);
    float* xproj   = ws + F_XPROJ;
    float* gatesB  = ws + F_GATESB;
    float* hfF     = ws + F_HF;
    float* hbLast  = ws + F_HBLAST;
    float* seSum2  = ws + F_SESUM2;
    float* seSc2   = ws + F_SESC2;
    float* seSum3  = ws + F_SESUM3;
    float* seSc3   = ws + F_SESC3;
    uint4* whh4    = (uint4*)(ws + F_WHHB);
    unsigned short* wkb  = (unsigned short*)(ws + F_WKB);
    unsigned short* wkb3 = (unsigned short*)(ws + F_WKB3);
    unsigned short* wihFb = (unsigned short*)(ws + F_WIHF);
    unsigned short* wihBb = (unsigned short*)(ws + F_WIHB);
    unsigned short* p1T = (unsigned short*)(ws + F_BIGA);   // B*1024*64 bf16
    float* h2      = ws + F_BIGB;   // B*128*1024 f32
    unsigned short* p2T = (unsigned short*)(ws + F_BIGA);   // reuse after p1T dead
    float* h3      = ws + F_BIGB;   // reuse after h2 dead

    hipMemsetAsync(seSum2, 0, 16384 * sizeof(float), stream);
    hipMemsetAsync(seSum3, 0, 32768 * sizeof(float), stream);

    // Frequency branch
    stft_kernel<<<B * NFR, 256, 0, stream>>>(x_cont, mag);
    gate_kernel<<<B, 128, 0, stream>>>(mag, gate_w1, gate_b1, gate_w2, gate_b2, topi, gw);
    expert_conv1_kernel<<<dim3(B, 2, 2), 512, 0, stream>>>(mag, topi, exp_w1, exp_b1, eh1);
    expert_conv2_kernel<<<dim3(B, 2, 2), 512, 0, stream>>>(eh1, topi, exp_w2, exp_b2, sel);

    // Line branch
    prep_wkb_kernel<<<160, 256, 0, stream>>>(lw2, wkb);
    line1_kernel<<<dim3(B, 4), 256, 0, stream>>>(x_norm, lw1, lb1, p1T);
    line2_mfma_kernel<<<dim3(B, 8), 256, 0, stream>>>(p1T, wkb, lb2, h2, seSum2);
    se2_kernel<<<B, 128, 0, stream>>>(seSum2, se2_w1, se2_w2, seSc2);
    pool2t_kernel<<<B, 256, 0, stream>>>(h2, seSc2, p2T);
    prep_wkb3_kernel<<<384, 256, 0, stream>>>(lw3, wkb3);
    line3_mfma_kernel<<<dim3(B, 2, 2), 256, 0, stream>>>(p2T, wkb3, lb3, h3, seSum3);
    se3_kernel<<<B, 256, 0, stream>>>(seSum3, se3_w1, se3_w2, seSc3);
    pool3_kernel<<<2048, 256, 0, stream>>>(h3, seSc3, lineFeat);

    // Fuse features -> comb bf16 (33*128, 512)
    comb_kernel<<<2048, 256, 0, stream>>>(sel, gw, lineFeat, combB);

    // Pack LSTM input-projection weights to bf16
    pack_bf16_kernel<<<512, 256, 0, stream>>>(wih_f, wihFb, 1024 * 512);
    pack_bf16_kernel<<<512, 256, 0, stream>>>(wih_b, wihBb, 1024 * 512);

    // LSTM input projections via MFMA + backward-step gates
    gemm_mfma_kernel<<<dim3(33, 8), 256, 0, stream>>>(combB, wihFb, bih_f, bhh_f, xproj);
    gemm_mfma_kernel<<<dim3(1, 8), 256, 0, stream>>>(combB + (size_t)4096 * 512, wihBb, bih_b, bhh_b, gatesB);
    lstm_bwd_tail_kernel<<<B, 256, 0, stream>>>(gatesB, hbLast);

    // Forward LSTM recurrence (2 batches/block + 8 LDS weight slices)
    prep_whh4_kernel<<<128, 256, 0, stream>>>(whh_f, whh4);
    lstm_fused_kernel<<<64, 1024, 0, stream>>>(xproj, whh4, hfF);

    // Head
    ffn_kernel<<<B, 256, 0, stream>>>(hfF, hbLast, ffn_w1, ffn_b1, ffn_w2, ffn_b2, (float*)d_out);
}

// Round 11
// 644.917 us; speedup vs baseline: 1.1817x; 1.1817x over previous
//
#include <hip/hip_runtime.h>
#include <math.h>

namespace {
constexpr int B = 128;
constexpr int L = 4096;
constexpr int NBIN = 129;
constexpr int NFR = 33;

// workspace offsets (in floats), all multiples of 64
constexpr size_t F_MAG    = 0;                       // B*129*33 = 544896
constexpr size_t F_GW     = F_MAG + 544896;          // 256
constexpr size_t F_TOPI   = F_GW + 256;              // 256 (ints)
constexpr size_t F_EH1    = F_TOPI + 256;            // B*2*256*33 = 2162688
constexpr size_t F_SEL    = F_EH1 + 2162688;         // 2162688
constexpr size_t F_LINEF  = F_SEL + 2162688;         // B*256*64 = 2097152
constexpr size_t F_COMB   = F_LINEF + 2097152;       // 2162688 (bf16 [4224][512] uses half)
constexpr size_t F_XPROJ  = F_COMB + 2162688;        // 33*128*1024 = 4325376
constexpr size_t F_GATESB = F_XPROJ + 4325376;       // 128*1024 = 131072
constexpr size_t F_HF     = F_GATESB + 131072;       // 32768
constexpr size_t F_HBLAST = F_HF + 32768;            // 32768
constexpr size_t F_SESUM2 = F_HBLAST + 32768;        // 16384
constexpr size_t F_SESC2  = F_SESUM2 + 16384;        // 16384
constexpr size_t F_SESUM3 = F_SESC2 + 16384;         // 32768
constexpr size_t F_SESC3  = F_SESUM3 + 32768;        // 32768
constexpr size_t F_WHHB   = F_SESC3 + 32768;         // 131072 (bf16 whh, uint4 layout, 512KB)
constexpr size_t F_WKB    = F_WHHB + 131072;         // 20480 floats (128*320 bf16)
constexpr size_t F_WKB3   = F_WKB + 20480;           // 49152 floats (256*384 bf16)
constexpr size_t F_WIHF   = F_WKB3 + 49152;          // 262144 floats (1024*512 bf16)
constexpr size_t F_WIHB   = F_WIHF + 262144;         // 262144 floats
constexpr size_t F_BIGA   = F_WIHB + 262144;         // 8388608  (p1T bf16, later p2T bf16)
constexpr size_t F_BIGB   = F_BIGA + 8388608;        // 16777216 (h2, later h3)
}

typedef __attribute__((ext_vector_type(8))) short bf16x8;
typedef __attribute__((ext_vector_type(4))) float f32x4;

__device__ __forceinline__ float sigm(float x) { return 1.0f / (1.0f + expf(-x)); }

// fast saturating-safe gate functions (v_exp_f32 path)
__device__ __forceinline__ float fsigm(float x) { return 1.0f / (1.0f + __expf(-x)); }
__device__ __forceinline__ float ftanh(float x) { return 1.0f - 2.0f / (__expf(2.0f * x) + 1.0f); }

__device__ __forceinline__ unsigned int f2bf_rne(float f) {
    unsigned int u = __float_as_uint(f);
    return (u + 0x7FFFu + ((u >> 16) & 1u)) >> 16;
}

__device__ __forceinline__ float bflo(unsigned int u) { return __uint_as_float(u << 16); }
__device__ __forceinline__ float bfhi(unsigned int u) { return __uint_as_float(u & 0xFFFF0000u); }

// ---------------- STFT: per (b,frame) block, table DFT, 129 bins ----------------
__global__ __launch_bounds__(256) void stft_kernel(const float* __restrict__ x,
                                                   float* __restrict__ mag)
{
    int bf = blockIdx.x;            // b*33 + f
    int b = bf / NFR, f = bf % NFR;
    int tid = threadIdx.x;
    __shared__ float tbl[256];
    __shared__ float fx[256];
    tbl[tid] = cosf(6.28318530717958647692f * (float)tid / 256.0f);
    __syncthreads();
    {
        int j = f * 128 + tid - 128;
        if (j < 0) j = -j;
        else if (j >= L) j = 2 * L - 2 - j;
        float win = 0.5f * (1.0f - tbl[tid]);
        fx[tid] = x[(size_t)b * L + j] * win;
    }
    __syncthreads();
    if (tid < NBIN) {
        float re = 0.f, im = 0.f;
        int m = 0;
        for (int n = 0; n < 256; ++n) {
            float v = fx[n];
            re += v * tbl[m];
            im += v * tbl[(m + 192) & 255];
            m = (m + tid) & 255;
        }
        mag[((size_t)b * NBIN + tid) * NFR + f] = sqrtf(re * re + im * im);
    }
}

// ---------------- pooled mean + gate MLP + top2 ----------------
__global__ __launch_bounds__(128) void gate_kernel(const float* __restrict__ mag,
                                                   const float* __restrict__ w1,
                                                   const float* __restrict__ b1,
                                                   const float* __restrict__ w2,
                                                   const float* __restrict__ b2,
                                                   int* __restrict__ topi,
                                                   float* __restrict__ gw)
{
    int b = blockIdx.x, tid = threadIdx.x;
    __shared__ float pooled[NBIN];
    __shared__ float h1[128];
    __shared__ float lg[8];
    for (int k = tid; k < NBIN; k += 128) {
        const float* mp = mag + ((size_t)b * NBIN + k) * NFR;
        float s = 0.f;
        for (int f = 0; f < NFR; ++f) s += mp[f];
        pooled[k] = s * (1.0f / 33.0f);
    }
    __syncthreads();
    {
        float acc = b1[tid];
        const float* wr = w1 + tid * NBIN;
        for (int k = 0; k < NBIN; ++k) acc += pooled[k] * wr[k];
        h1[tid] = fmaxf(acc, 0.f);
    }
    __syncthreads();
    if (tid < 8) {
        float a = b2[tid];
        const float* w = w2 + tid * 128;
        for (int j = 0; j < 128; ++j) a += h1[j] * w[j];
        lg[tid] = a;
    }
    __syncthreads();
    if (tid == 0) {
        int i0 = 0; float v0 = lg[0];
        for (int e = 1; e < 8; ++e) if (lg[e] > v0) { v0 = lg[e]; i0 = e; }
        int i1 = -1; float v1 = -3.0e38f;
        for (int e = 0; e < 8; ++e) { if (e == i0) continue; if (lg[e] > v1) { v1 = lg[e]; i1 = e; } }
        float m = fmaxf(v0, v1);
        float e0 = expf(v0 - m), e1 = expf(v1 - m);
        float inv = 1.0f / (e0 + e1);
        topi[b * 2 + 0] = i0; topi[b * 2 + 1] = i1;
        gw[b * 2 + 0] = e0 * inv; gw[b * 2 + 1] = e1 * inv;
    }
}

// ---------------- expert conv1: 129ch -> 256ch, k=5, pad=2, len 33 ----------------
__global__ __launch_bounds__(512) void expert_conv1_kernel(const float* __restrict__ mag,
                                                           const int* __restrict__ topi,
                                                           const float* __restrict__ W,
                                                           const float* __restrict__ Bb,
                                                           float* __restrict__ out)
{
    int b = blockIdx.x, slot = blockIdx.y;
    int e = topi[b * 2 + slot];
    __shared__ float sm[129 * 37 + 16];
    int tid = threadIdx.x;
    for (int i = tid; i < 129 * 37 + 16; i += 512) sm[i] = 0.f;
    __syncthreads();
    for (int i = tid; i < 129 * 33; i += 512) {
        int ic = i / 33, t = i % 33;
        sm[ic * 37 + 2 + t] = mag[((size_t)b * NBIN + ic) * NFR + t];
    }
    __syncthreads();
    int oc = (blockIdx.z << 7) + (tid >> 2);
    int tq = tid & 3;
    int t0 = tq * 9;
    int nt = (tq == 3) ? 6 : 9;
    float acc[9];
#pragma unroll
    for (int i = 0; i < 9; ++i) acc[i] = 0.f;
    const float* wp = W + ((size_t)e * 256 + oc) * (129 * 5);
    for (int ic = 0; ic < 129; ++ic) {
        const float* wr = wp + ic * 5;
        const float* sr = sm + ic * 37 + t0;
        float w0 = wr[0], w1 = wr[1], w2 = wr[2], w3 = wr[3], w4 = wr[4];
#pragma unroll
        for (int t = 0; t < 9; ++t)
            acc[t] += w0 * sr[t] + w1 * sr[t + 1] + w2 * sr[t + 2] + w3 * sr[t + 3] + w4 * sr[t + 4];
    }
    float bias = Bb[e * 256 + oc];
    float* op = out + (((size_t)b * 2 + slot) * 256 + oc) * NFR + t0;
    for (int t = 0; t < nt; ++t) op[t] = fmaxf(acc[t] + bias, 0.f);
}

// ---------------- expert conv2: 256ch -> 256ch, k=3, pad=1, len 33 ----------------
__global__ __launch_bounds__(512) void expert_conv2_kernel(const float* __restrict__ eh1,
                                                           const int* __restrict__ topi,
                                                           const float* __restrict__ W,
                                                           const float* __restrict__ Bb,
                                                           float* __restrict__ out)
{
    int b = blockIdx.x, slot = blockIdx.y;
    int e = topi[b * 2 + slot];
    __shared__ float sm[256 * 37 + 16];
    int tid = threadIdx.x;
    for (int i = tid; i < 256 * 37 + 16; i += 512) sm[i] = 0.f;
    __syncthreads();
    for (int i = tid; i < 256 * 33; i += 512) {
        int ic = i / 33, t = i % 33;
        sm[ic * 37 + 2 + t] = eh1[(((size_t)b * 2 + slot) * 256 + ic) * NFR + t];
    }
    __syncthreads();
    int oc = (blockIdx.z << 7) + (tid >> 2);
    int tq = tid & 3;
    int t0 = tq * 9;
    int nt = (tq == 3) ? 6 : 9;
    float acc[9];
#pragma unroll
    for (int i = 0; i < 9; ++i) acc[i] = 0.f;
    const float* wp = W + ((size_t)e * 256 + oc) * (256 * 3);
    for (int ic = 0; ic < 256; ++ic) {
        const float* wr = wp + ic * 3;
        const float* sr = sm + ic * 37 + t0;
        float w0 = wr[0], w1 = wr[1], w2 = wr[2];
#pragma unroll
        for (int t = 0; t < 9; ++t)
            acc[t] += w0 * sr[t + 1] + w1 * sr[t + 2] + w2 * sr[t + 3];
    }
    float bias = Bb[e * 256 + oc];
    float* op = out + (((size_t)b * 2 + slot) * 256 + oc) * NFR + t0;
    for (int t = 0; t < nt; ++t) op[t] = fmaxf(acc[t] + bias, 0.f);
}

// ---------------- line conv1 (1->64, k7, pad3) + relu + maxpool4 -> p1T bf16 [b][t][ic] ----------------
__global__ __launch_bounds__(256) void line1_kernel(const float* __restrict__ x,
                                                    const float* __restrict__ lw1,
                                                    const float* __restrict__ lb1,
                                                    unsigned short* __restrict__ p1T)
{
    int b = blockIdx.x;
    int P0 = blockIdx.y * 256;
    __shared__ float sx[1032];
    __shared__ float w[448];
    __shared__ float bb[64];
    __shared__ unsigned short sT[256 * 65];
    int tid = threadIdx.x;
    for (int i = tid; i < 448; i += 256) w[i] = lw1[i];
    for (int i = tid; i < 64; i += 256) bb[i] = lb1[i];
    int base = 4 * P0 - 3;
    for (int i = tid; i < 1032; i += 256) {
        int g = base + i;
        sx[i] = (g >= 0 && g < L) ? x[(size_t)b * L + g] : 0.f;
    }
    __syncthreads();
    int p = tid;
    for (int oc = 0; oc < 64; ++oc) {
        const float* wr = w + oc * 7;
        float best = -3.0e38f;
#pragma unroll
        for (int q = 0; q < 4; ++q) {
            const float* s = sx + 4 * p + q;
            float v = wr[0]*s[0] + wr[1]*s[1] + wr[2]*s[2] + wr[3]*s[3] + wr[4]*s[4] + wr[5]*s[5] + wr[6]*s[6];
            best = fmaxf(best, v);
        }
        float v = fmaxf(best + bb[oc], 0.f);
        sT[p * 65 + oc] = (unsigned short)f2bf_rne(v);
    }
    __syncthreads();
    unsigned int* outw = reinterpret_cast<unsigned int*>(p1T);
    for (int i2 = tid; i2 < 256 * 32; i2 += 256) {
        int row = i2 >> 5, dw = i2 & 31;
        unsigned int lo = sT[row * 65 + dw * 2];
        unsigned int hi = sT[row * 65 + dw * 2 + 1];
        outw[((size_t)b * 1024 + P0 + row) * 32 + dw] = lo | (hi << 16);
    }
}

// ---------------- prep line2 weights: lw2[oc][ic][k] f32 -> wkb[oc][K'=k*64+ic] bf16 ----------------
__global__ __launch_bounds__(256) void prep_wkb_kernel(const float* __restrict__ W,
                                                       unsigned short* __restrict__ wkb)
{
    int idx = blockIdx.x * 256 + threadIdx.x;   // 128*320
    if (idx >= 128 * 320) return;
    int oc = idx / 320, K = idx % 320;
    int k = K >> 6, ic = K & 63;
    wkb[idx] = (unsigned short)f2bf_rne(W[oc * 320 + ic * 5 + k]);
}

// ---------------- line conv2 via MFMA: C[128 oc][1024 t] = W[128][320] x im2col ----------------
__global__ __launch_bounds__(256) void line2_mfma_kernel(const unsigned short* __restrict__ p1T,
                                                         const unsigned short* __restrict__ wkb,
                                                         const float* __restrict__ lb2,
                                                         float* __restrict__ h2,
                                                         float* __restrict__ seSum2)
{
    int b = blockIdx.x;
    int t0 = blockIdx.y * 128;
    __shared__ __align__(16) unsigned short wl[128 * 320];   // 80 KB, XOR-swizzled 16B chunks
    __shared__ __align__(16) unsigned short inT[132 * 64];   // 16.9 KB, rows j=t_rel+2, XOR-swizzled
    __shared__ float bias[128];
    int tid = threadIdx.x;

    for (int idx = tid; idx < 128 * 40; idx += 256) {
        int oc = idx / 40, ch = idx % 40;
        int swz = (ch & ~7) | ((ch & 7) ^ (oc & 7));
        *reinterpret_cast<uint4*>(&wl[oc * 320 + swz * 8]) =
            *reinterpret_cast<const uint4*>(&wkb[oc * 320 + ch * 8]);
    }
    for (int idx = tid; idx < 132 * 8; idx += 256) {
        int j = idx / 8, ch = idx % 8;
        int t = t0 - 2 + j;
        uint4 v = make_uint4(0u, 0u, 0u, 0u);
        if (t >= 0 && t < 1024)
            v = *reinterpret_cast<const uint4*>(&p1T[((size_t)b * 1024 + t) * 64 + ch * 8]);
        int swz = ch ^ (j & 7);
        *reinterpret_cast<uint4*>(&inT[j * 64 + swz * 8]) = v;
    }
    if (tid < 128) bias[tid] = lb2[tid];
    __syncthreads();

    int lane = tid & 63;
    int w = tid >> 6;
    int l15 = lane & 15, g = lane >> 4;

    f32x4 acc[8][2];
#pragma unroll
    for (int ot = 0; ot < 8; ++ot) {
        acc[ot][0] = (f32x4){0.f, 0.f, 0.f, 0.f};
        acc[ot][1] = (f32x4){0.f, 0.f, 0.f, 0.f};
    }

    for (int ks = 0; ks < 10; ++ks) {
        int k = ks >> 1;
        bf16x8 bf0, bf1;
        {
            int j = w * 32 + l15 + k;
            int ch = (ks & 1) * 4 + g;
            bf0 = *reinterpret_cast<const bf16x8*>(&inT[j * 64 + (ch ^ (j & 7)) * 8]);
            int j1 = j + 16;
            bf1 = *reinterpret_cast<const bf16x8*>(&inT[j1 * 64 + (ch ^ (j1 & 7)) * 8]);
        }
#pragma unroll
        for (int ot = 0; ot < 8; ++ot) {
            int row = ot * 16 + l15;
            int ch = ks * 4 + g;
            int swz = (ch & ~7) | ((ch & 7) ^ (row & 7));
            bf16x8 af = *reinterpret_cast<const bf16x8*>(&wl[row * 320 + swz * 8]);
            acc[ot][0] = __builtin_amdgcn_mfma_f32_16x16x32_bf16(af, bf0, acc[ot][0], 0, 0, 0);
            acc[ot][1] = __builtin_amdgcn_mfma_f32_16x16x32_bf16(af, bf1, acc[ot][1], 0, 0, 0);
        }
    }

    int tcol = t0 + w * 32 + l15;
#pragma unroll
    for (int ot = 0; ot < 8; ++ot) {
#pragma unroll
        for (int r = 0; r < 4; ++r) {
            int oc = ot * 16 + g * 4 + r;
            float bv = bias[oc];
            float v0 = fmaxf(acc[ot][0][r] + bv, 0.f);
            float v1 = fmaxf(acc[ot][1][r] + bv, 0.f);
            float* hp = h2 + ((size_t)b * 128 + oc) * 1024 + tcol;
            hp[0] = v0;
            hp[16] = v1;
            float s = v0 + v1;
            s += __shfl_xor(s, 1);
            s += __shfl_xor(s, 2);
            s += __shfl_xor(s, 4);
            s += __shfl_xor(s, 8);
            if (l15 == 0) atomicAdd(&seSum2[b * 128 + oc], s);
        }
    }
}

// ---------------- SE for stage2 ----------------
__global__ __launch_bounds__(128) void se2_kernel(const float* __restrict__ seSum2,
                                                  const float* __restrict__ w1,
                                                  const float* __restrict__ w2,
                                                  float* __restrict__ seScale2)
{
    int b = blockIdx.x, tid = threadIdx.x;
    __shared__ float y[128];
    __shared__ float z[32];
    y[tid] = seSum2[b * 128 + tid] * (1.0f / 1024.0f);
    __syncthreads();
    if (tid < 32) {
        float a = 0.f;
        const float* wr = w1 + tid * 128;
        for (int c = 0; c < 128; ++c) a += y[c] * wr[c];
        z[tid] = fmaxf(a, 0.f);
    }
    __syncthreads();
    {
        float a = 0.f;
        const float* wr = w2 + tid * 32;
        for (int j = 0; j < 32; ++j) a += z[j] * wr[j];
        seScale2[b * 128 + tid] = sigm(a);
    }
}

// ---------------- pool2 + transpose: p2T bf16 [b][p][ic] = scale*maxpool4(h2) ----------------
__global__ __launch_bounds__(256) void pool2t_kernel(const float* __restrict__ h2,
                                                     const float* __restrict__ seScale2,
                                                     unsigned short* __restrict__ p2T)
{
    int b = blockIdx.x, p = threadIdx.x;   // p in [0,256)
    __shared__ unsigned short sT[256 * 129];
    for (int c = 0; c < 128; ++c) {
        float4 v = *reinterpret_cast<const float4*>(&h2[((size_t)b * 128 + c) * 1024 + 4 * p]);
        float m = fmaxf(fmaxf(v.x, v.y), fmaxf(v.z, v.w)) * seScale2[b * 128 + c];
        sT[p * 129 + c] = (unsigned short)f2bf_rne(m);
    }
    __syncthreads();
    unsigned int* out = reinterpret_cast<unsigned int*>(p2T);
    for (int idx = p; idx < 256 * 64; idx += 256) {
        int row = idx >> 6, dw = idx & 63;
        unsigned int lo = sT[row * 129 + dw * 2];
        unsigned int hi = sT[row * 129 + dw * 2 + 1];
        out[((size_t)b * 256 + row) * 64 + dw] = lo | (hi << 16);
    }
}

// ---------------- prep line3 weights: lw3[oc][ic][k] f32 -> wkb3[oc][K'=k*128+ic] bf16 ----------------
__global__ __launch_bounds__(256) void prep_wkb3_kernel(const float* __restrict__ W,
                                                        unsigned short* __restrict__ wkb3)
{
    int idx = blockIdx.x * 256 + threadIdx.x;   // 256*384
    if (idx >= 256 * 384) return;
    int oc = idx / 384, K = idx % 384;
    int k = K >> 7, ic = K & 127;
    wkb3[idx] = (unsigned short)f2bf_rne(W[oc * 384 + ic * 3 + k]);
}

// ---------------- line conv3 via MFMA: per block 128oc x 128t, K'=384 ----------------
__global__ __launch_bounds__(256) void line3_mfma_kernel(const unsigned short* __restrict__ p2T,
                                                         const unsigned short* __restrict__ wkb3,
                                                         const float* __restrict__ lb3,
                                                         float* __restrict__ h3,
                                                         float* __restrict__ seSum3)
{
    int b = blockIdx.x;
    int oc0 = blockIdx.y * 128;
    int t0 = blockIdx.z * 128;
    __shared__ __align__(16) unsigned short wl[128 * 384];   // 96 KB
    __shared__ __align__(16) unsigned short inT[130 * 128];  // 32.5 KB
    __shared__ float bias[128];
    int tid = threadIdx.x;

    for (int idx = tid; idx < 128 * 48; idx += 256) {
        int oc = idx / 48, ch = idx % 48;
        int swz = (ch & ~7) | ((ch & 7) ^ (oc & 7));
        *reinterpret_cast<uint4*>(&wl[oc * 384 + swz * 8]) =
            *reinterpret_cast<const uint4*>(&wkb3[(size_t)(oc0 + oc) * 384 + ch * 8]);
    }
    for (int idx = tid; idx < 130 * 16; idx += 256) {
        int j = idx / 16, ch = idx % 16;
        int t = t0 - 1 + j;
        uint4 v = make_uint4(0u, 0u, 0u, 0u);
        if (t >= 0 && t < 256)
            v = *reinterpret_cast<const uint4*>(&p2T[((size_t)b * 256 + t) * 128 + ch * 8]);
        int swz = ch ^ (j & 15);
        *reinterpret_cast<uint4*>(&inT[j * 128 + swz * 8]) = v;
    }
    if (tid < 128) bias[tid] = lb3[oc0 + tid];
    __syncthreads();

    int lane = tid & 63;
    int w = tid >> 6;
    int l15 = lane & 15, g = lane >> 4;

    f32x4 acc[8][2];
#pragma unroll
    for (int ot = 0; ot < 8; ++ot) {
        acc[ot][0] = (f32x4){0.f, 0.f, 0.f, 0.f};
        acc[ot][1] = (f32x4){0.f, 0.f, 0.f, 0.f};
    }

    for (int ks = 0; ks < 12; ++ks) {
        int k = ks >> 2;                 // tap
        int ch = (ks & 3) * 4 + g;       // ic chunk within row
        bf16x8 bf0, bf1;
        {
            int j = w * 32 + l15 + k;
            bf0 = *reinterpret_cast<const bf16x8*>(&inT[j * 128 + (ch ^ (j & 15)) * 8]);
            int j1 = j + 16;
            bf1 = *reinterpret_cast<const bf16x8*>(&inT[j1 * 128 + (ch ^ (j1 & 15)) * 8]);
        }
#pragma unroll
        for (int ot = 0; ot < 8; ++ot) {
            int row = ot * 16 + l15;
            int wch = ks * 4 + g;
            int swz = (wch & ~7) | ((wch & 7) ^ (row & 7));
            bf16x8 af = *reinterpret_cast<const bf16x8*>(&wl[row * 384 + swz * 8]);
            acc[ot][0] = __builtin_amdgcn_mfma_f32_16x16x32_bf16(af, bf0, acc[ot][0], 0, 0, 0);
            acc[ot][1] = __builtin_amdgcn_mfma_f32_16x16x32_bf16(af, bf1, acc[ot][1], 0, 0, 0);
        }
    }

    int tcol = t0 + w * 32 + l15;
#pragma unroll
    for (int ot = 0; ot < 8; ++ot) {
#pragma unroll
        for (int r = 0; r < 4; ++r) {
            int ocl = ot * 16 + g * 4 + r;
            int oc = oc0 + ocl;
            float bv = bias[ocl];
            float v0 = fmaxf(acc[ot][0][r] + bv, 0.f);
            float v1 = fmaxf(acc[ot][1][r] + bv, 0.f);
            float* hp = h3 + ((size_t)b * 256 + oc) * 256 + tcol;
            hp[0] = v0;
            hp[16] = v1;
            float s = v0 + v1;
            s += __shfl_xor(s, 1);
            s += __shfl_xor(s, 2);
            s += __shfl_xor(s, 4);
            s += __shfl_xor(s, 8);
            if (l15 == 0) atomicAdd(&seSum3[b * 256 + oc], s);
        }
    }
}

// ---------------- SE for stage3 ----------------
__global__ __launch_bounds__(256) void se3_kernel(const float* __restrict__ seSum3,
                                                  const float* __restrict__ w1,
                                                  const float* __restrict__ w2,
                                                  float* __restrict__ seScale3)
{
    int b = blockIdx.x, tid = threadIdx.x;
    __shared__ float y[256];
    __shared__ float z[64];
    y[tid] = seSum3[b * 256 + tid] * (1.0f / 256.0f);
    __syncthreads();
    if (tid < 64) {
        float a = 0.f;
        const float* wr = w1 + tid * 256;
        for (int c = 0; c < 256; ++c) a += y[c] * wr[c];
        z[tid] = fmaxf(a, 0.f);
    }
    __syncthreads();
    {
        float a = 0.f;
        const float* wr = w2 + tid * 64;
        for (int j = 0; j < 64; ++j) a += z[j] * wr[j];
        seScale3[b * 256 + tid] = sigm(a);
    }
}

// ---------------- pool stage3: lineFeat = scale * maxpool4(h3) ----------------
__global__ __launch_bounds__(256) void pool3_kernel(const float* __restrict__ h3,
                                                    const float* __restrict__ seScale3,
                                                    float* __restrict__ lineFeat)
{
    const int total = 128 * 256 * 64;
    for (int idx = blockIdx.x * 256 + threadIdx.x; idx < total; idx += gridDim.x * 256) {
        int b = idx >> 14;
        int c = (idx >> 6) & 255;
        int p = idx & 63;
        const float* hp = h3 + (((size_t)b * 256 + c) * 256) + 4 * p;
        float v = fmaxf(fmaxf(hp[0], hp[1]), fmaxf(hp[2], hp[3]));
        lineFeat[idx] = v * seScale3[b * 256 + c];
    }
}

// ---------------- build comb bf16 (33*128, 512): freq combine + line interp ----------------
__global__ __launch_bounds__(256) void comb_kernel(const float* __restrict__ sel,
                                                   const float* __restrict__ gw,
                                                   const float* __restrict__ lineFeat,
                                                   unsigned short* __restrict__ combB)
{
    const int total = 33 * 128 * 512;
    for (int idx = blockIdx.x * 256 + threadIdx.x; idx < total; idx += gridDim.x * 256) {
        int c = idx & 511;
        int r = idx >> 9;         // t*128 + b
        int b = r & 127;
        int t = r >> 7;
        float v;
        if (c < 256) {
            float g0 = gw[b * 2 + 0], g1 = gw[b * 2 + 1];
            v = g0 * sel[(((size_t)b * 2 + 0) * 256 + c) * NFR + t]
              + g1 * sel[(((size_t)b * 2 + 1) * 256 + c) * NFR + t];
        } else {
            int cc = c - 256;
            float xc = ((float)t + 0.5f) * (64.0f / 33.0f) - 0.5f;
            xc = fminf(fmaxf(xc, 0.0f), 63.0f);
            int lo = (int)floorf(xc);
            int hi = lo + 1; if (hi > 63) hi = 63;
            float w = xc - (float)lo;
            const float* lp = lineFeat + ((size_t)b * 256 + cc) * 64;
            v = lp[lo] * (1.0f - w) + lp[hi] * w;
        }
        combB[idx] = (unsigned short)f2bf_rne(v);
    }
}

// ---------------- generic f32 -> bf16 pack (n multiple of 4) ----------------
__global__ __launch_bounds__(256) void pack_bf16_kernel(const float* __restrict__ in,
                                                        unsigned short* __restrict__ out,
                                                        int n)
{
    int i = (blockIdx.x * 256 + threadIdx.x) * 4;
    if (i >= n) return;
    float4 v = *reinterpret_cast<const float4*>(in + i);
    uint2 w;
    w.x = f2bf_rne(v.x) | (f2bf_rne(v.y) << 16);
    w.y = f2bf_rne(v.z) | (f2bf_rne(v.w) << 16);
    *reinterpret_cast<uint2*>(out + i) = w;
}

// ---------------- MFMA GEMM: out[M][1024] = A[M][512]bf16 x W[1024][512]^T bf16 + b1 + b2 ----
// grid (M/128, 8). 256 thr / 4 waves. Fragment pattern = line3_mfma (verified).
__global__ __launch_bounds__(256) void gemm_mfma_kernel(const unsigned short* __restrict__ A,
                                                        const unsigned short* __restrict__ W,
                                                        const float* __restrict__ b1,
                                                        const float* __restrict__ b2,
                                                        float* __restrict__ out)
{
    int row0 = blockIdx.x * 128;
    int col0 = blockIdx.y * 128;
    __shared__ __align__(16) unsigned short As[128 * 64];
    __shared__ __align__(16) unsigned short Bs[128 * 64];
    __shared__ float bias[128];
    int tid = threadIdx.x;
    if (tid < 128) bias[tid] = b1[col0 + tid] + b2[col0 + tid];
    int lane = tid & 63, w = tid >> 6, l15 = lane & 15, g = lane >> 4;

    f32x4 acc[8][2];
#pragma unroll
    for (int ot = 0; ot < 8; ++ot) {
        acc[ot][0] = (f32x4){0.f, 0.f, 0.f, 0.f};
        acc[ot][1] = (f32x4){0.f, 0.f, 0.f, 0.f};
    }

    for (int kc = 0; kc < 8; ++kc) {
        __syncthreads();
        for (int idx = tid; idx < 1024; idx += 256) {
            int r = idx >> 3, ch = idx & 7;
            int swz = ch ^ (r & 7);
            *reinterpret_cast<uint4*>(&As[r * 64 + swz * 8]) =
                *reinterpret_cast<const uint4*>(&A[(size_t)(row0 + r) * 512 + kc * 64 + ch * 8]);
            *reinterpret_cast<uint4*>(&Bs[r * 64 + swz * 8]) =
                *reinterpret_cast<const uint4*>(&W[(size_t)(col0 + r) * 512 + kc * 64 + ch * 8]);
        }
        __syncthreads();
#pragma unroll
        for (int ks = 0; ks < 2; ++ks) {
            int ch = ks * 4 + g;
            int j = w * 32 + l15;
            bf16x8 bf0 = *reinterpret_cast<const bf16x8*>(&As[j * 64 + (ch ^ (j & 7)) * 8]);
            int j1 = j + 16;
            bf16x8 bf1 = *reinterpret_cast<const bf16x8*>(&As[j1 * 64 + (ch ^ (j1 & 7)) * 8]);
#pragma unroll
            for (int ot = 0; ot < 8; ++ot) {
                int row = ot * 16 + l15;
                bf16x8 af = *reinterpret_cast<const bf16x8*>(&Bs[row * 64 + (ch ^ (row & 7)) * 8]);
                acc[ot][0] = __builtin_amdgcn_mfma_f32_16x16x32_bf16(af, bf0, acc[ot][0], 0, 0, 0);
                acc[ot][1] = __builtin_amdgcn_mfma_f32_16x16x32_bf16(af, bf1, acc[ot][1], 0, 0, 0);
            }
        }
    }

    int rbase = row0 + w * 32 + l15;
#pragma unroll
    for (int ot = 0; ot < 8; ++ot) {
#pragma unroll
        for (int r = 0; r < 4; ++r) {
            int ocl = ot * 16 + g * 4 + r;
            float bv = bias[ocl];
            out[(size_t)rbase * 1024 + col0 + ocl] = acc[ot][0][r] + bv;
            out[(size_t)(rbase + 16) * 1024 + col0 + ocl] = acc[ot][1][r] + bv;
        }
    }
}

// ---------------- pack whh_f (1024,256) -> bf16 whh4: uint4[k8*1024 + j] ----------------
__global__ __launch_bounds__(256) void prep_whh4_kernel(const float* __restrict__ W,
                                                        uint4* __restrict__ whh4)
{
    int idx = blockIdx.x * 256 + threadIdx.x;   // 32768 (k8, j) pairs
    int k8 = idx >> 10, j = idx & 1023;
    const float* src = W + (size_t)j * 256 + k8 * 8;
    float4 v0 = *reinterpret_cast<const float4*>(src);
    float4 v1 = *reinterpret_cast<const float4*>(src + 4);
    uint4 w;
    w.x = f2bf_rne(v0.x) | (f2bf_rne(v0.y) << 16);
    w.y = f2bf_rne(v0.z) | (f2bf_rne(v0.w) << 16);
    w.z = f2bf_rne(v1.x) | (f2bf_rne(v1.y) << 16);
    w.w = f2bf_rne(v1.z) | (f2bf_rne(v1.w) << 16);
    whh4[(size_t)k8 * 1024 + j] = w;
}

// ---------------- fused forward LSTM: all 33 steps in one kernel ----------------
// R9 PROVEN version (199 us): 128 blocks x 1024 thr, 1 batch/block, weights streamed
// from L2 as uint4 each step. Do NOT add register-resident weights (R7/R8: 64-VGPR cap
// -> spills, 1 GB scratch). Do NOT go to 2 batches/block with LDS staging (R10: grid
// halves to 64 blocks -> 64 CUs idle-starved, 310 us).
__global__ __launch_bounds__(1024) void lstm_fused_kernel(const float* __restrict__ xproj,
                                                          const uint4* __restrict__ whh4,
                                                          float* __restrict__ hfinal)
{
    int b = blockIdx.x;
    int j = threadIdx.x;
    __shared__ __align__(16) float h[256];
    __shared__ float cc[256];
    __shared__ float g[1024];
    if (j < 256) { h[j] = 0.f; cc[j] = 0.f; }
    __syncthreads();
    const uint4* wp = whh4 + j;
    for (int t = 0; t < 33; ++t) {
        float a0 = xproj[(size_t)t * 131072 + (size_t)b * 1024 + j];
        float a1 = 0.f;
#pragma unroll 8
        for (int k8 = 0; k8 < 32; ++k8) {
            uint4 w = wp[k8 << 10];
            float4 h0 = *reinterpret_cast<const float4*>(&h[k8 * 8]);
            float4 h1 = *reinterpret_cast<const float4*>(&h[k8 * 8 + 4]);
            a0 += bflo(w.x) * h0.x + bfhi(w.x) * h0.y + bflo(w.y) * h0.z + bfhi(w.y) * h0.w;
            a1 += bflo(w.z) * h1.x + bfhi(w.z) * h1.y + bflo(w.w) * h1.z + bfhi(w.w) * h1.w;
        }
        g[j] = a0 + a1;
        __syncthreads();
        if (j < 256) {
            float gi = g[j], gf = g[256 + j], gz = g[512 + j], go = g[768 + j];
            float c = fsigm(gf) * cc[j] + fsigm(gi) * ftanh(gz);
            cc[j] = c;
            h[j] = fsigm(go) * ftanh(c);
        }
        __syncthreads();
    }
    if (j < 256) hfinal[b * 256 + j] = h[j];
}

// ---------------- backward LSTM single step from zero state ----------------
__global__ __launch_bounds__(256) void lstm_bwd_tail_kernel(const float* __restrict__ gatesB,
                                                            float* __restrict__ hbLast)
{
    int b = blockIdx.x, u = threadIdx.x;
    const float* g = gatesB + (size_t)b * 1024;
    float ai = g[u], ag = g[512 + u], ao = g[768 + u];
    float c = sigm(ai) * tanhf(ag);
    hbLast[b * 256 + u] = sigm(ao) * tanhf(c);
}

// ---------------- FFN head ----------------
__global__ __launch_bounds__(256) void ffn_kernel(const float* __restrict__ hf,
                                                  const float* __restrict__ hb,
                                                  const float* __restrict__ w1,
                                                  const float* __restrict__ b1,
                                                  const float* __restrict__ w2,
                                                  const float* __restrict__ b2,
                                                  float* __restrict__ out)
{
    int b = blockIdx.x, tid = threadIdx.x;
    __shared__ float last[512];
    __shared__ float red[256];
    last[tid] = hf[b * 256 + tid];
    last[256 + tid] = hb[b * 256 + tid];
    __syncthreads();
    float a = b1[tid];
    const float* wr = w1 + (size_t)tid * 512;
    for (int k = 0; k < 512; ++k) a += last[k] * wr[k];
    red[tid] = fmaxf(a, 0.f) * w2[tid];
    __syncthreads();
    for (int s = 128; s > 0; s >>= 1) {
        if (tid < s) red[tid] += red[tid + s];
        __syncthreads();
    }
    if (tid == 0) out[b] = red[0] + b2[0];
}

extern "C" void kernel_launch(void* const* d_in, const int* in_sizes, int n_in,
                              void* d_out, int out_size, void* d_ws, size_t ws_size,
                              hipStream_t stream)
{
    (void)in_sizes; (void)n_in; (void)out_size; (void)ws_size;
    const float* x_cont = (const float*)d_in[0];
    const float* x_norm = (const float*)d_in[1];
    const float* gate_w1 = (const float*)d_in[2];
    const float* gate_b1 = (const float*)d_in[3];
    const float* gate_w2 = (const float*)d_in[4];
    const float* gate_b2 = (const float*)d_in[5];
    const float* exp_w1 = (const float*)d_in[6];
    const float* exp_b1 = (const float*)d_in[7];
    const float* exp_w2 = (const float*)d_in[8];
    const float* exp_b2 = (const float*)d_in[9];
    const float* lw1 = (const float*)d_in[10];
    const float* lb1 = (const float*)d_in[11];
    const float* lw2 = (const float*)d_in[12];
    const float* lb2 = (const float*)d_in[13];
    const float* se2_w1 = (const float*)d_in[14];
    const float* se2_w2 = (const float*)d_in[15];
    const float* lw3 = (const float*)d_in[16];
    const float* lb3 = (const float*)d_in[17];
    const float* se3_w1 = (const float*)d_in[18];
    const float* se3_w2 = (const float*)d_in[19];
    const float* wih_f = (const float*)d_in[20];
    const float* whh_f = (const float*)d_in[21];
    const float* bih_f = (const float*)d_in[22];
    const float* bhh_f = (const float*)d_in[23];
    const float* wih_b = (const float*)d_in[24];
    const float* whh_b = (const float*)d_in[25];
    const float* bih_b = (const float*)d_in[26];
    const float* bhh_b = (const float*)d_in[27];
    const float* ffn_w1 = (const float*)d_in[28];
    const float* ffn_b1 = (const float*)d_in[29];
    const float* ffn_w2 = (const float*)d_in[30];
    const float* ffn_b2 = (const float*)d_in[31];

    float* ws = (float*)d_ws;
    float* mag     = ws + F_MAG;
    float* gw      = ws + F_GW;
    int*   topi    = (int*)(ws + F_TOPI);
    float* eh1     = ws + F_EH1;
    float* sel     = ws + F_SEL;
    float* lineFeat= ws + F_LINEF;
    unsigned short* combB = (unsigned short*)(ws + F_COMB);
    float* xproj   = ws + F_XPROJ;
    float* gatesB  = ws + F_GATESB;
    float* hfF     = ws + F_HF;
    float* hbLast  = ws + F_HBLAST;
    float* seSum2  = ws + F_SESUM2;
    float* seSc2   = ws + F_SESC2;
    float* seSum3  = ws + F_SESUM3;
    float* seSc3   = ws + F_SESC3;
    uint4* whh4    = (uint4*)(ws + F_WHHB);
    unsigned short* wkb  = (unsigned short*)(ws + F_WKB);
    unsigned short* wkb3 = (unsigned short*)(ws + F_WKB3);
    unsigned short* wihFb = (unsigned short*)(ws + F_WIHF);
    unsigned short* wihBb = (unsigned short*)(ws + F_WIHB);
    unsigned short* p1T = (unsigned short*)(ws + F_BIGA);   // B*1024*64 bf16
    float* h2      = ws + F_BIGB;   // B*128*1024 f32
    unsigned short* p2T = (unsigned short*)(ws + F_BIGA);   // reuse after p1T dead
    float* h3      = ws + F_BIGB;   // reuse after h2 dead

    hipMemsetAsync(seSum2, 0, 16384 * sizeof(float), stream);
    hipMemsetAsync(seSum3, 0, 32768 * sizeof(float), stream);

    // Frequency branch
    stft_kernel<<<B * NFR, 256, 0, stream>>>(x_cont, mag);
    gate_kernel<<<B, 128, 0, stream>>>(mag, gate_w1, gate_b1, gate_w2, gate_b2, topi, gw);
    expert_conv1_kernel<<<dim3(B, 2, 2), 512, 0, stream>>>(mag, topi, exp_w1, exp_b1, eh1);
    expert_conv2_kernel<<<dim3(B, 2, 2), 512, 0, stream>>>(eh1, topi, exp_w2, exp_b2, sel);

    // Line branch
    prep_wkb_kernel<<<160, 256, 0, stream>>>(lw2, wkb);
    line1_kernel<<<dim3(B, 4), 256, 0, stream>>>(x_norm, lw1, lb1, p1T);
    line2_mfma_kernel<<<dim3(B, 8), 256, 0, stream>>>(p1T, wkb, lb2, h2, seSum2);
    se2_kernel<<<B, 128, 0, stream>>>(seSum2, se2_w1, se2_w2, seSc2);
    pool2t_kernel<<<B, 256, 0, stream>>>(h2, seSc2, p2T);
    prep_wkb3_kernel<<<384, 256, 0, stream>>>(lw3, wkb3);
    line3_mfma_kernel<<<dim3(B, 2, 2), 256, 0, stream>>>(p2T, wkb3, lb3, h3, seSum3);
    se3_kernel<<<B, 256, 0, stream>>>(seSum3, se3_w1, se3_w2, seSc3);
    pool3_kernel<<<2048, 256, 0, stream>>>(h3, seSc3, lineFeat);

    // Fuse features -> comb bf16 (33*128, 512)
    comb_kernel<<<2048, 256, 0, stream>>>(sel, gw, lineFeat, combB);

    // Pack LSTM input-projection weights to bf16
    pack_bf16_kernel<<<512, 256, 0, stream>>>(wih_f, wihFb, 1024 * 512);
    pack_bf16_kernel<<<512, 256, 0, stream>>>(wih_b, wihBb, 1024 * 512);

    // LSTM input projections via MFMA + backward-step gates
    gemm_mfma_kernel<<<dim3(33, 8), 256, 0, stream>>>(combB, wihFb, bih_f, bhh_f, xproj);
    gemm_mfma_kernel<<<dim3(1, 8), 256, 0, stream>>>(combB + (size_t)4096 * 512, wihBb, bih_b, bhh_b, gatesB);
    lstm_bwd_tail_kernel<<<B, 256, 0, stream>>>(gatesB, hbLast);

    // Forward LSTM recurrence (R9 proven streaming structure, 128 blocks)
    prep_whh4_kernel<<<128, 256, 0, stream>>>(whh_f, whh4);
    lstm_fused_kernel<<<B, 1024, 0, stream>>>(xproj, whh4, hfF);

    // Head
    ffn_kernel<<<B, 256, 0, stream>>>(hfF, hbLast, ffn_w1, ffn_b1, ffn_w2, ffn_b2, (float*)d_out);
}

// Round 12
// 591.698 us; speedup vs baseline: 1.2880x; 1.0899x over previous
//
#include <hip/hip_runtime.h>
#include <math.h>

namespace {
constexpr int B = 128;
constexpr int L = 4096;
constexpr int NBIN = 129;
constexpr int NFR = 33;

// workspace offsets (in floats)
constexpr size_t F_MAG    = 0;                       // B*129*33 = 544896
constexpr size_t F_GW     = F_MAG + 544896;          // 256
constexpr size_t F_TOPI   = F_GW + 256;              // 256 (ints)
constexpr size_t F_EH1    = F_TOPI + 256;            // now eh1T bf16 (2162688 ush) in 2162688 floats
constexpr size_t F_SEL    = F_EH1 + 2162688;         // 2162688
constexpr size_t F_LINEF  = F_SEL + 2162688;         // 2097152
constexpr size_t F_COMB   = F_LINEF + 2097152;       // bf16 comb
constexpr size_t F_XPROJ  = F_COMB + 2162688;        // 4325376 (early: wkbE1/wkbE2/magT; late: xproj)
constexpr size_t F_GATESB = F_XPROJ + 4325376;
constexpr size_t F_HF     = F_GATESB + 131072;
constexpr size_t F_HBLAST = F_HF + 32768;
constexpr size_t F_SESUM2 = F_HBLAST + 32768;
constexpr size_t F_SESC2  = F_SESUM2 + 16384;
constexpr size_t F_SESUM3 = F_SESC2 + 16384;
constexpr size_t F_SESC3  = F_SESUM3 + 32768;
constexpr size_t F_WHHB   = F_SESC3 + 32768;         // 131072
constexpr size_t F_WKB    = F_WHHB + 131072;         // 20480
constexpr size_t F_WKB3   = F_WKB + 20480;           // 49152
constexpr size_t F_WIHF   = F_WKB3 + 49152;          // 262144
constexpr size_t F_WIHB   = F_WIHF + 262144;         // 262144
constexpr size_t F_BIGA   = F_WIHB + 262144;         // 8388608
constexpr size_t F_BIGB   = F_BIGA + 8388608;        // 16777216
// aliases inside F_XPROJ region (dead before xproj is written):
constexpr size_t A_WKBE1  = F_XPROJ;                 // 8*256*704 ush = 720896 floats
constexpr size_t A_WKBE2  = F_XPROJ + 720896;        // 8*256*768 ush = 786432 floats
constexpr size_t A_MAGT   = F_XPROJ + 1507328;       // 128*33*136 ush = 287232 floats (< 4325376 total)
}

typedef __attribute__((ext_vector_type(8))) short bf16x8;
typedef __attribute__((ext_vector_type(4))) float f32x4;

__device__ __forceinline__ float sigm(float x) { return 1.0f / (1.0f + expf(-x)); }
__device__ __forceinline__ float fsigm(float x) { return 1.0f / (1.0f + __expf(-x)); }
__device__ __forceinline__ float ftanh(float x) { return 1.0f - 2.0f / (__expf(2.0f * x) + 1.0f); }

__device__ __forceinline__ unsigned int f2bf_rne(float f) {
    unsigned int u = __float_as_uint(f);
    return (u + 0x7FFFu + ((u >> 16) & 1u)) >> 16;
}
__device__ __forceinline__ float bflo(unsigned int u) { return __uint_as_float(u << 16); }
__device__ __forceinline__ float bfhi(unsigned int u) { return __uint_as_float(u & 0xFFFF0000u); }

// ---------------- STFT: per (b,frame) block, table DFT; writes mag f32 + magT bf16 ----------------
__global__ __launch_bounds__(256) void stft_kernel(const float* __restrict__ x,
                                                   float* __restrict__ mag,
                                                   unsigned short* __restrict__ magT)
{
    int bf = blockIdx.x;            // b*33 + f
    int b = bf / NFR, f = bf % NFR;
    int tid = threadIdx.x;
    __shared__ float tbl[256];
    __shared__ float fx[256];
    tbl[tid] = cosf(6.28318530717958647692f * (float)tid / 256.0f);
    __syncthreads();
    {
        int j = f * 128 + tid - 128;
        if (j < 0) j = -j;
        else if (j >= L) j = 2 * L - 2 - j;
        float win = 0.5f * (1.0f - tbl[tid]);
        fx[tid] = x[(size_t)b * L + j] * win;
    }
    __syncthreads();
    if (tid < NBIN) {
        float re = 0.f, im = 0.f;
        int m = 0;
        for (int n = 0; n < 256; ++n) {
            float v = fx[n];
            re += v * tbl[m];
            im += v * tbl[(m + 192) & 255];
            m = (m + tid) & 255;
        }
        float val = sqrtf(re * re + im * im);
        mag[((size_t)b * NBIN + tid) * NFR + f] = val;
        magT[((size_t)b * NFR + f) * 136 + tid] = (unsigned short)f2bf_rne(val);
    } else if (tid < 136) {
        magT[((size_t)b * NFR + f) * 136 + tid] = 0;
    }
}

// ---------------- pooled mean + gate MLP + top2 ----------------
__global__ __launch_bounds__(128) void gate_kernel(const float* __restrict__ mag,
                                                   const float* __restrict__ w1,
                                                   const float* __restrict__ b1,
                                                   const float* __restrict__ w2,
                                                   const float* __restrict__ b2,
                                                   int* __restrict__ topi,
                                                   float* __restrict__ gw)
{
    int b = blockIdx.x, tid = threadIdx.x;
    __shared__ float pooled[NBIN];
    __shared__ float h1[128];
    __shared__ float lg[8];
    for (int k = tid; k < NBIN; k += 128) {
        const float* mp = mag + ((size_t)b * NBIN + k) * NFR;
        float s = 0.f;
        for (int f = 0; f < NFR; ++f) s += mp[f];
        pooled[k] = s * (1.0f / 33.0f);
    }
    __syncthreads();
    {
        float acc = b1[tid];
        const float* wr = w1 + tid * NBIN;
        for (int k = 0; k < NBIN; ++k) acc += pooled[k] * wr[k];
        h1[tid] = fmaxf(acc, 0.f);
    }
    __syncthreads();
    if (tid < 8) {
        float a = b2[tid];
        const float* w = w2 + tid * 128;
        for (int j = 0; j < 128; ++j) a += h1[j] * w[j];
        lg[tid] = a;
    }
    __syncthreads();
    if (tid == 0) {
        int i0 = 0; float v0 = lg[0];
        for (int e = 1; e < 8; ++e) if (lg[e] > v0) { v0 = lg[e]; i0 = e; }
        int i1 = -1; float v1 = -3.0e38f;
        for (int e = 0; e < 8; ++e) { if (e == i0) continue; if (lg[e] > v1) { v1 = lg[e]; i1 = e; } }
        float m = fmaxf(v0, v1);
        float e0 = expf(v0 - m), e1 = expf(v1 - m);
        float inv = 1.0f / (e0 + e1);
        topi[b * 2 + 0] = i0; topi[b * 2 + 1] = i1;
        gw[b * 2 + 0] = e0 * inv; gw[b * 2 + 1] = e1 * inv;
    }
}

// ---------------- prep expert conv1 weights: -> wkbE1[e][oc][K'=704], K'=k*136+ic ----------------
__global__ __launch_bounds__(256) void prep_wkbE1_kernel(const float* __restrict__ W,
                                                         unsigned short* __restrict__ out)
{
    int idx = blockIdx.x * 256 + threadIdx.x;   // 8*256*704 = 1441792
    if (idx >= 8 * 256 * 704) return;
    int eo = idx / 704, K = idx % 704;          // eo = e*256+oc
    int k = K / 136, ic = K - k * 136;
    float v = (k < 5 && ic < 129) ? W[((size_t)eo * 129 + ic) * 5 + k] : 0.f;
    out[idx] = (unsigned short)f2bf_rne(v);
}

// ---------------- prep expert conv2 weights: -> wkbE2[e][oc][K'=768], K'=k*256+ic ----------------
__global__ __launch_bounds__(256) void prep_wkbE2_kernel(const float* __restrict__ W,
                                                         unsigned short* __restrict__ out)
{
    int idx = blockIdx.x * 256 + threadIdx.x;   // 8*256*768 = 1572864
    if (idx >= 8 * 256 * 768) return;
    int eo = idx / 768, K = idx % 768;
    int k = K >> 8, ic = K & 255;
    out[idx] = (unsigned short)f2bf_rne(W[((size_t)eo * 256 + ic) * 3 + k]);
}

// ---------------- expert conv1 via MFMA: C[64 oc][48 t], K'=704 (22 steps) ----------------
// grid (B, 2 slots, 4 oc-quarters). 256 thr / 4 waves; wave w owns oc-tile w.
__global__ __launch_bounds__(256) void expert_conv1_mfma(const unsigned short* __restrict__ magT,
                                                         const int* __restrict__ topi,
                                                         const unsigned short* __restrict__ wkbE1,
                                                         const float* __restrict__ Bb,
                                                         unsigned short* __restrict__ eh1T)
{
    int b = blockIdx.x, slot = blockIdx.y, ocq = blockIdx.z;
    int e = topi[b * 2 + slot];
    __shared__ __align__(16) unsigned short wl[64 * 704];   // 88 KB
    __shared__ __align__(16) unsigned short inT[37 * 136];  // 10 KB (stride 272B == 2-way, no swz)
    __shared__ float bias[64];
    int tid = threadIdx.x;
    for (int idx = tid; idx < 64 * 88; idx += 256) {
        int oc = idx / 88, ch = idx % 88;
        int swz = (ch & ~7) | ((ch & 7) ^ (oc & 7));
        *reinterpret_cast<uint4*>(&wl[oc * 704 + swz * 8]) =
            *reinterpret_cast<const uint4*>(&wkbE1[((size_t)(e * 256 + ocq * 64 + oc)) * 704 + ch * 8]);
    }
    for (int idx = tid; idx < 37 * 17; idx += 256) {
        int j = idx / 17, ch = idx % 17;
        int tp = j - 2;
        uint4 v = make_uint4(0u, 0u, 0u, 0u);
        if (tp >= 0 && tp < 33)
            v = *reinterpret_cast<const uint4*>(&magT[((size_t)b * NFR + tp) * 136 + ch * 8]);
        *reinterpret_cast<uint4*>(&inT[j * 136 + ch * 8]) = v;
    }
    if (tid < 64) bias[tid] = Bb[e * 256 + ocq * 64 + tid];
    __syncthreads();

    int lane = tid & 63, w = tid >> 6, l15 = lane & 15, g = lane >> 4;
    f32x4 acc[3];
#pragma unroll
    for (int n = 0; n < 3; ++n) acc[n] = (f32x4){0.f, 0.f, 0.f, 0.f};

    int row = w * 16 + l15;
    for (int ks = 0; ks < 22; ++ks) {
        int ch = ks * 4 + g;                       // 0..87
        bf16x8 af = *reinterpret_cast<const bf16x8*>(
            &wl[row * 704 + (((ch & ~7) | ((ch & 7) ^ (row & 7)))) * 8]);
        int ce = ch > 84 ? 84 : ch;                // chunks 85..87 have zero weights
        int k = ce / 17, icc = ce - k * 17;
#pragma unroll
        for (int n = 0; n < 3; ++n) {
            int t = n * 16 + l15;
            int j = t + k; if (j > 36) j = 36;     // dead columns clamped (discarded)
            bf16x8 bf = *reinterpret_cast<const bf16x8*>(&inT[j * 136 + icc * 8]);
            acc[n] = __builtin_amdgcn_mfma_f32_16x16x32_bf16(af, bf, acc[n], 0, 0, 0);
        }
    }
#pragma unroll
    for (int n = 0; n < 3; ++n) {
        int t = n * 16 + l15;
        if (t < 33) {
            float v0 = fmaxf(acc[n][0] + bias[w * 16 + g * 4 + 0], 0.f);
            float v1 = fmaxf(acc[n][1] + bias[w * 16 + g * 4 + 1], 0.f);
            float v2 = fmaxf(acc[n][2] + bias[w * 16 + g * 4 + 2], 0.f);
            float v3 = fmaxf(acc[n][3] + bias[w * 16 + g * 4 + 3], 0.f);
            uint2 pk;
            pk.x = f2bf_rne(v0) | (f2bf_rne(v1) << 16);
            pk.y = f2bf_rne(v2) | (f2bf_rne(v3) << 16);
            *reinterpret_cast<uint2*>(
                &eh1T[(((size_t)(b * 2 + slot)) * NFR + t) * 256 + ocq * 64 + w * 16 + g * 4]) = pk;
        }
    }
}

// ---------------- expert conv2 via MFMA: C[64 oc][48 t], K'=768 (24 steps) ----------------
// grid (B, 2 slots, 4 oc-quarters)
__global__ __launch_bounds__(256) void expert_conv2_mfma(const unsigned short* __restrict__ eh1T,
                                                         const int* __restrict__ topi,
                                                         const unsigned short* __restrict__ wkbE2,
                                                         const float* __restrict__ Bb,
                                                         float* __restrict__ sel)
{
    int b = blockIdx.x, slot = blockIdx.y, ocq = blockIdx.z;
    int e = topi[b * 2 + slot];
    __shared__ __align__(16) unsigned short wl[64 * 768];   // 96 KB
    __shared__ __align__(16) unsigned short inT[35 * 256];  // 17.5 KB, XOR-swizzled
    __shared__ float bias[64];
    int tid = threadIdx.x;
    for (int idx = tid; idx < 64 * 96; idx += 256) {
        int oc = idx / 96, ch = idx % 96;
        int swz = (ch & ~7) | ((ch & 7) ^ (oc & 7));
        *reinterpret_cast<uint4*>(&wl[oc * 768 + swz * 8]) =
            *reinterpret_cast<const uint4*>(&wkbE2[((size_t)(e * 256 + ocq * 64 + oc)) * 768 + ch * 8]);
    }
    for (int idx = tid; idx < 35 * 32; idx += 256) {
        int j = idx / 32, ch = idx % 32;
        int tp = j - 1;
        uint4 v = make_uint4(0u, 0u, 0u, 0u);
        if (tp >= 0 && tp < 33)
            v = *reinterpret_cast<const uint4*>(&eh1T[(((size_t)(b * 2 + slot)) * NFR + tp) * 256 + ch * 8]);
        int swz = (ch & ~15) | ((ch & 15) ^ (j & 15));
        *reinterpret_cast<uint4*>(&inT[j * 256 + swz * 8]) = v;
    }
    if (tid < 64) bias[tid] = Bb[e * 256 + ocq * 64 + tid];
    __syncthreads();

    int lane = tid & 63, w = tid >> 6, l15 = lane & 15, g = lane >> 4;
    f32x4 acc[3];
#pragma unroll
    for (int n = 0; n < 3; ++n) acc[n] = (f32x4){0.f, 0.f, 0.f, 0.f};

    int row = w * 16 + l15;
    for (int ks = 0; ks < 24; ++ks) {
        int ch = ks * 4 + g;                       // 0..95
        bf16x8 af = *reinterpret_cast<const bf16x8*>(
            &wl[row * 768 + (((ch & ~7) | ((ch & 7) ^ (row & 7)))) * 8]);
        int k = ch >> 5, icc = ch & 31;
#pragma unroll
        for (int n = 0; n < 3; ++n) {
            int t = n * 16 + l15;
            int j = t + k; if (j > 34) j = 34;
            int sz = (icc & ~15) | ((icc & 15) ^ (j & 15));
            bf16x8 bf = *reinterpret_cast<const bf16x8*>(&inT[j * 256 + sz * 8]);
            acc[n] = __builtin_amdgcn_mfma_f32_16x16x32_bf16(af, bf, acc[n], 0, 0, 0);
        }
    }
#pragma unroll
    for (int n = 0; n < 3; ++n) {
        int t = n * 16 + l15;
        if (t < 33) {
#pragma unroll
            for (int r = 0; r < 4; ++r) {
                int oc = ocq * 64 + w * 16 + g * 4 + r;
                float v = fmaxf(acc[n][r] + bias[w * 16 + g * 4 + r], 0.f);
                sel[(((size_t)b * 2 + slot) * 256 + oc) * NFR + t] = v;
            }
        }
    }
}

// ---------------- line conv1 (1->64, k7, pad3) + relu + maxpool4 -> p1T bf16 [b][t][ic] ----------------
__global__ __launch_bounds__(256) void line1_kernel(const float* __restrict__ x,
                                                    const float* __restrict__ lw1,
                                                    const float* __restrict__ lb1,
                                                    unsigned short* __restrict__ p1T)
{
    int b = blockIdx.x;
    int P0 = blockIdx.y * 256;
    __shared__ float sx[1032];
    __shared__ float w[448];
    __shared__ float bb[64];
    __shared__ unsigned short sT[256 * 65];
    int tid = threadIdx.x;
    for (int i = tid; i < 448; i += 256) w[i] = lw1[i];
    for (int i = tid; i < 64; i += 256) bb[i] = lb1[i];
    int base = 4 * P0 - 3;
    for (int i = tid; i < 1032; i += 256) {
        int g = base + i;
        sx[i] = (g >= 0 && g < L) ? x[(size_t)b * L + g] : 0.f;
    }
    __syncthreads();
    int p = tid;
    for (int oc = 0; oc < 64; ++oc) {
        const float* wr = w + oc * 7;
        float best = -3.0e38f;
#pragma unroll
        for (int q = 0; q < 4; ++q) {
            const float* s = sx + 4 * p + q;
            float v = wr[0]*s[0] + wr[1]*s[1] + wr[2]*s[2] + wr[3]*s[3] + wr[4]*s[4] + wr[5]*s[5] + wr[6]*s[6];
            best = fmaxf(best, v);
        }
        float v = fmaxf(best + bb[oc], 0.f);
        sT[p * 65 + oc] = (unsigned short)f2bf_rne(v);
    }
    __syncthreads();
    unsigned int* outw = reinterpret_cast<unsigned int*>(p1T);
    for (int i2 = tid; i2 < 256 * 32; i2 += 256) {
        int row = i2 >> 5, dw = i2 & 31;
        unsigned int lo = sT[row * 65 + dw * 2];
        unsigned int hi = sT[row * 65 + dw * 2 + 1];
        outw[((size_t)b * 1024 + P0 + row) * 32 + dw] = lo | (hi << 16);
    }
}

// ---------------- prep line2 weights ----------------
__global__ __launch_bounds__(256) void prep_wkb_kernel(const float* __restrict__ W,
                                                       unsigned short* __restrict__ wkb)
{
    int idx = blockIdx.x * 256 + threadIdx.x;
    if (idx >= 128 * 320) return;
    int oc = idx / 320, K = idx % 320;
    int k = K >> 6, ic = K & 63;
    wkb[idx] = (unsigned short)f2bf_rne(W[oc * 320 + ic * 5 + k]);
}

// ---------------- line conv2 via MFMA ----------------
__global__ __launch_bounds__(256) void line2_mfma_kernel(const unsigned short* __restrict__ p1T,
                                                         const unsigned short* __restrict__ wkb,
                                                         const float* __restrict__ lb2,
                                                         float* __restrict__ h2,
                                                         float* __restrict__ seSum2)
{
    int b = blockIdx.x;
    int t0 = blockIdx.y * 128;
    __shared__ __align__(16) unsigned short wl[128 * 320];
    __shared__ __align__(16) unsigned short inT[132 * 64];
    __shared__ float bias[128];
    int tid = threadIdx.x;

    for (int idx = tid; idx < 128 * 40; idx += 256) {
        int oc = idx / 40, ch = idx % 40;
        int swz = (ch & ~7) | ((ch & 7) ^ (oc & 7));
        *reinterpret_cast<uint4*>(&wl[oc * 320 + swz * 8]) =
            *reinterpret_cast<const uint4*>(&wkb[oc * 320 + ch * 8]);
    }
    for (int idx = tid; idx < 132 * 8; idx += 256) {
        int j = idx / 8, ch = idx % 8;
        int t = t0 - 2 + j;
        uint4 v = make_uint4(0u, 0u, 0u, 0u);
        if (t >= 0 && t < 1024)
            v = *reinterpret_cast<const uint4*>(&p1T[((size_t)b * 1024 + t) * 64 + ch * 8]);
        int swz = ch ^ (j & 7);
        *reinterpret_cast<uint4*>(&inT[j * 64 + swz * 8]) = v;
    }
    if (tid < 128) bias[tid] = lb2[tid];
    __syncthreads();

    int lane = tid & 63;
    int w = tid >> 6;
    int l15 = lane & 15, g = lane >> 4;

    f32x4 acc[8][2];
#pragma unroll
    for (int ot = 0; ot < 8; ++ot) {
        acc[ot][0] = (f32x4){0.f, 0.f, 0.f, 0.f};
        acc[ot][1] = (f32x4){0.f, 0.f, 0.f, 0.f};
    }

    for (int ks = 0; ks < 10; ++ks) {
        int k = ks >> 1;
        bf16x8 bf0, bf1;
        {
            int j = w * 32 + l15 + k;
            int ch = (ks & 1) * 4 + g;
            bf0 = *reinterpret_cast<const bf16x8*>(&inT[j * 64 + (ch ^ (j & 7)) * 8]);
            int j1 = j + 16;
            bf1 = *reinterpret_cast<const bf16x8*>(&inT[j1 * 64 + (ch ^ (j1 & 7)) * 8]);
        }
#pragma unroll
        for (int ot = 0; ot < 8; ++ot) {
            int row = ot * 16 + l15;
            int ch = ks * 4 + g;
            int swz = (ch & ~7) | ((ch & 7) ^ (row & 7));
            bf16x8 af = *reinterpret_cast<const bf16x8*>(&wl[row * 320 + swz * 8]);
            acc[ot][0] = __builtin_amdgcn_mfma_f32_16x16x32_bf16(af, bf0, acc[ot][0], 0, 0, 0);
            acc[ot][1] = __builtin_amdgcn_mfma_f32_16x16x32_bf16(af, bf1, acc[ot][1], 0, 0, 0);
        }
    }

    int tcol = t0 + w * 32 + l15;
#pragma unroll
    for (int ot = 0; ot < 8; ++ot) {
#pragma unroll
        for (int r = 0; r < 4; ++r) {
            int oc = ot * 16 + g * 4 + r;
            float bv = bias[oc];
            float v0 = fmaxf(acc[ot][0][r] + bv, 0.f);
            float v1 = fmaxf(acc[ot][1][r] + bv, 0.f);
            float* hp = h2 + ((size_t)b * 128 + oc) * 1024 + tcol;
            hp[0] = v0;
            hp[16] = v1;
            float s = v0 + v1;
            s += __shfl_xor(s, 1);
            s += __shfl_xor(s, 2);
            s += __shfl_xor(s, 4);
            s += __shfl_xor(s, 8);
            if (l15 == 0) atomicAdd(&seSum2[b * 128 + oc], s);
        }
    }
}

// ---------------- SE for stage2 ----------------
__global__ __launch_bounds__(128) void se2_kernel(const float* __restrict__ seSum2,
                                                  const float* __restrict__ w1,
                                                  const float* __restrict__ w2,
                                                  float* __restrict__ seScale2)
{
    int b = blockIdx.x, tid = threadIdx.x;
    __shared__ float y[128];
    __shared__ float z[32];
    y[tid] = seSum2[b * 128 + tid] * (1.0f / 1024.0f);
    __syncthreads();
    if (tid < 32) {
        float a = 0.f;
        const float* wr = w1 + tid * 128;
        for (int c = 0; c < 128; ++c) a += y[c] * wr[c];
        z[tid] = fmaxf(a, 0.f);
    }
    __syncthreads();
    {
        float a = 0.f;
        const float* wr = w2 + tid * 32;
        for (int j = 0; j < 32; ++j) a += z[j] * wr[j];
        seScale2[b * 128 + tid] = sigm(a);
    }
}

// ---------------- pool2 + transpose ----------------
__global__ __launch_bounds__(256) void pool2t_kernel(const float* __restrict__ h2,
                                                     const float* __restrict__ seScale2,
                                                     unsigned short* __restrict__ p2T)
{
    int b = blockIdx.x, p = threadIdx.x;
    __shared__ unsigned short sT[256 * 129];
    for (int c = 0; c < 128; ++c) {
        float4 v = *reinterpret_cast<const float4*>(&h2[((size_t)b * 128 + c) * 1024 + 4 * p]);
        float m = fmaxf(fmaxf(v.x, v.y), fmaxf(v.z, v.w)) * seScale2[b * 128 + c];
        sT[p * 129 + c] = (unsigned short)f2bf_rne(m);
    }
    __syncthreads();
    unsigned int* out = reinterpret_cast<unsigned int*>(p2T);
    for (int idx = p; idx < 256 * 64; idx += 256) {
        int row = idx >> 6, dw = idx & 63;
        unsigned int lo = sT[row * 129 + dw * 2];
        unsigned int hi = sT[row * 129 + dw * 2 + 1];
        out[((size_t)b * 256 + row) * 64 + dw] = lo | (hi << 16);
    }
}

// ---------------- prep line3 weights ----------------
__global__ __launch_bounds__(256) void prep_wkb3_kernel(const float* __restrict__ W,
                                                        unsigned short* __restrict__ wkb3)
{
    int idx = blockIdx.x * 256 + threadIdx.x;
    if (idx >= 256 * 384) return;
    int oc = idx / 384, K = idx % 384;
    int k = K >> 7, ic = K & 127;
    wkb3[idx] = (unsigned short)f2bf_rne(W[oc * 384 + ic * 3 + k]);
}

// ---------------- line conv3 via MFMA ----------------
__global__ __launch_bounds__(256) void line3_mfma_kernel(const unsigned short* __restrict__ p2T,
                                                         const unsigned short* __restrict__ wkb3,
                                                         const float* __restrict__ lb3,
                                                         float* __restrict__ h3,
                                                         float* __restrict__ seSum3)
{
    int b = blockIdx.x;
    int oc0 = blockIdx.y * 128;
    int t0 = blockIdx.z * 128;
    __shared__ __align__(16) unsigned short wl[128 * 384];
    __shared__ __align__(16) unsigned short inT[130 * 128];
    __shared__ float bias[128];
    int tid = threadIdx.x;

    for (int idx = tid; idx < 128 * 48; idx += 256) {
        int oc = idx / 48, ch = idx % 48;
        int swz = (ch & ~7) | ((ch & 7) ^ (oc & 7));
        *reinterpret_cast<uint4*>(&wl[oc * 384 + swz * 8]) =
            *reinterpret_cast<const uint4*>(&wkb3[(size_t)(oc0 + oc) * 384 + ch * 8]);
    }
    for (int idx = tid; idx < 130 * 16; idx += 256) {
        int j = idx / 16, ch = idx % 16;
        int t = t0 - 1 + j;
        uint4 v = make_uint4(0u, 0u, 0u, 0u);
        if (t >= 0 && t < 256)
            v = *reinterpret_cast<const uint4*>(&p2T[((size_t)b * 256 + t) * 128 + ch * 8]);
        int swz = ch ^ (j & 15);
        *reinterpret_cast<uint4*>(&inT[j * 128 + swz * 8]) = v;
    }
    if (tid < 128) bias[tid] = lb3[oc0 + tid];
    __syncthreads();

    int lane = tid & 63;
    int w = tid >> 6;
    int l15 = lane & 15, g = lane >> 4;

    f32x4 acc[8][2];
#pragma unroll
    for (int ot = 0; ot < 8; ++ot) {
        acc[ot][0] = (f32x4){0.f, 0.f, 0.f, 0.f};
        acc[ot][1] = (f32x4){0.f, 0.f, 0.f, 0.f};
    }

    for (int ks = 0; ks < 12; ++ks) {
        int k = ks >> 2;
        int ch = (ks & 3) * 4 + g;
        bf16x8 bf0, bf1;
        {
            int j = w * 32 + l15 + k;
            bf0 = *reinterpret_cast<const bf16x8*>(&inT[j * 128 + (ch ^ (j & 15)) * 8]);
            int j1 = j + 16;
            bf1 = *reinterpret_cast<const bf16x8*>(&inT[j1 * 128 + (ch ^ (j1 & 15)) * 8]);
        }
#pragma unroll
        for (int ot = 0; ot < 8; ++ot) {
            int row = ot * 16 + l15;
            int wch = ks * 4 + g;
            int swz = (wch & ~7) | ((wch & 7) ^ (row & 7));
            bf16x8 af = *reinterpret_cast<const bf16x8*>(&wl[row * 384 + swz * 8]);
            acc[ot][0] = __builtin_amdgcn_mfma_f32_16x16x32_bf16(af, bf0, acc[ot][0], 0, 0, 0);
            acc[ot][1] = __builtin_amdgcn_mfma_f32_16x16x32_bf16(af, bf1, acc[ot][1], 0, 0, 0);
        }
    }

    int tcol = t0 + w * 32 + l15;
#pragma unroll
    for (int ot = 0; ot < 8; ++ot) {
#pragma unroll
        for (int r = 0; r < 4; ++r) {
            int ocl = ot * 16 + g * 4 + r;
            int oc = oc0 + ocl;
            float bv = bias[ocl];
            float v0 = fmaxf(acc[ot][0][r] + bv, 0.f);
            float v1 = fmaxf(acc[ot][1][r] + bv, 0.f);
            float* hp = h3 + ((size_t)b * 256 + oc) * 256 + tcol;
            hp[0] = v0;
            hp[16] = v1;
            float s = v0 + v1;
            s += __shfl_xor(s, 1);
            s += __shfl_xor(s, 2);
            s += __shfl_xor(s, 4);
            s += __shfl_xor(s, 8);
            if (l15 == 0) atomicAdd(&seSum3[b * 256 + oc], s);
        }
    }
}

// ---------------- SE for stage3 ----------------
__global__ __launch_bounds__(256) void se3_kernel(const float* __restrict__ seSum3,
                                                  const float* __restrict__ w1,
                                                  const float* __restrict__ w2,
                                                  float* __restrict__ seScale3)
{
    int b = blockIdx.x, tid = threadIdx.x;
    __shared__ float y[256];
    __shared__ float z[64];
    y[tid] = seSum3[b * 256 + tid] * (1.0f / 256.0f);
    __syncthreads();
    if (tid < 64) {
        float a = 0.f;
        const float* wr = w1 + tid * 256;
        for (int c = 0; c < 256; ++c) a += y[c] * wr[c];
        z[tid] = fmaxf(a, 0.f);
    }
    __syncthreads();
    {
        float a = 0.f;
        const float* wr = w2 + tid * 64;
        for (int j = 0; j < 64; ++j) a += z[j] * wr[j];
        seScale3[b * 256 + tid] = sigm(a);
    }
}

// ---------------- pool stage3 ----------------
__global__ __launch_bounds__(256) void pool3_kernel(const float* __restrict__ h3,
                                                    const float* __restrict__ seScale3,
                                                    float* __restrict__ lineFeat)
{
    const int total = 128 * 256 * 64;
    for (int idx = blockIdx.x * 256 + threadIdx.x; idx < total; idx += gridDim.x * 256) {
        int b = idx >> 14;
        int c = (idx >> 6) & 255;
        int p = idx & 63;
        const float* hp = h3 + (((size_t)b * 256 + c) * 256) + 4 * p;
        float v = fmaxf(fmaxf(hp[0], hp[1]), fmaxf(hp[2], hp[3]));
        lineFeat[idx] = v * seScale3[b * 256 + c];
    }
}

// ---------------- build comb bf16 ----------------
__global__ __launch_bounds__(256) void comb_kernel(const float* __restrict__ sel,
                                                   const float* __restrict__ gw,
                                                   const float* __restrict__ lineFeat,
                                                   unsigned short* __restrict__ combB)
{
    const int total = 33 * 128 * 512;
    for (int idx = blockIdx.x * 256 + threadIdx.x; idx < total; idx += gridDim.x * 256) {
        int c = idx & 511;
        int r = idx >> 9;
        int b = r & 127;
        int t = r >> 7;
        float v;
        if (c < 256) {
            float g0 = gw[b * 2 + 0], g1 = gw[b * 2 + 1];
            v = g0 * sel[(((size_t)b * 2 + 0) * 256 + c) * NFR + t]
              + g1 * sel[(((size_t)b * 2 + 1) * 256 + c) * NFR + t];
        } else {
            int cc = c - 256;
            float xc = ((float)t + 0.5f) * (64.0f / 33.0f) - 0.5f;
            xc = fminf(fmaxf(xc, 0.0f), 63.0f);
            int lo = (int)floorf(xc);
            int hi = lo + 1; if (hi > 63) hi = 63;
            float w = xc - (float)lo;
            const float* lp = lineFeat + ((size_t)b * 256 + cc) * 64;
            v = lp[lo] * (1.0f - w) + lp[hi] * w;
        }
        combB[idx] = (unsigned short)f2bf_rne(v);
    }
}

// ---------------- generic f32 -> bf16 pack ----------------
__global__ __launch_bounds__(256) void pack_bf16_kernel(const float* __restrict__ in,
                                                        unsigned short* __restrict__ out,
                                                        int n)
{
    int i = (blockIdx.x * 256 + threadIdx.x) * 4;
    if (i >= n) return;
    float4 v = *reinterpret_cast<const float4*>(in + i);
    uint2 w;
    w.x = f2bf_rne(v.x) | (f2bf_rne(v.y) << 16);
    w.y = f2bf_rne(v.z) | (f2bf_rne(v.w) << 16);
    *reinterpret_cast<uint2*>(out + i) = w;
}

// ---------------- MFMA GEMM ----------------
__global__ __launch_bounds__(256) void gemm_mfma_kernel(const unsigned short* __restrict__ A,
                                                        const unsigned short* __restrict__ W,
                                                        const float* __restrict__ b1,
                                                        const float* __restrict__ b2,
                                                        float* __restrict__ out)
{
    int row0 = blockIdx.x * 128;
    int col0 = blockIdx.y * 128;
    __shared__ __align__(16) unsigned short As[128 * 64];
    __shared__ __align__(16) unsigned short Bs[128 * 64];
    __shared__ float bias[128];
    int tid = threadIdx.x;
    if (tid < 128) bias[tid] = b1[col0 + tid] + b2[col0 + tid];
    int lane = tid & 63, w = tid >> 6, l15 = lane & 15, g = lane >> 4;

    f32x4 acc[8][2];
#pragma unroll
    for (int ot = 0; ot < 8; ++ot) {
        acc[ot][0] = (f32x4){0.f, 0.f, 0.f, 0.f};
        acc[ot][1] = (f32x4){0.f, 0.f, 0.f, 0.f};
    }

    for (int kc = 0; kc < 8; ++kc) {
        __syncthreads();
        for (int idx = tid; idx < 1024; idx += 256) {
            int r = idx >> 3, ch = idx & 7;
            int swz = ch ^ (r & 7);
            *reinterpret_cast<uint4*>(&As[r * 64 + swz * 8]) =
                *reinterpret_cast<const uint4*>(&A[(size_t)(row0 + r) * 512 + kc * 64 + ch * 8]);
            *reinterpret_cast<uint4*>(&Bs[r * 64 + swz * 8]) =
                *reinterpret_cast<const uint4*>(&W[(size_t)(col0 + r) * 512 + kc * 64 + ch * 8]);
        }
        __syncthreads();
#pragma unroll
        for (int ks = 0; ks < 2; ++ks) {
            int ch = ks * 4 + g;
            int j = w * 32 + l15;
            bf16x8 bf0 = *reinterpret_cast<const bf16x8*>(&As[j * 64 + (ch ^ (j & 7)) * 8]);
            int j1 = j + 16;
            bf16x8 bf1 = *reinterpret_cast<const bf16x8*>(&As[j1 * 64 + (ch ^ (j1 & 7)) * 8]);
#pragma unroll
            for (int ot = 0; ot < 8; ++ot) {
                int row = ot * 16 + l15;
                bf16x8 af = *reinterpret_cast<const bf16x8*>(&Bs[row * 64 + (ch ^ (row & 7)) * 8]);
                acc[ot][0] = __builtin_amdgcn_mfma_f32_16x16x32_bf16(af, bf0, acc[ot][0], 0, 0, 0);
                acc[ot][1] = __builtin_amdgcn_mfma_f32_16x16x32_bf16(af, bf1, acc[ot][1], 0, 0, 0);
            }
        }
    }

    int rbase = row0 + w * 32 + l15;
#pragma unroll
    for (int ot = 0; ot < 8; ++ot) {
#pragma unroll
        for (int r = 0; r < 4; ++r) {
            int ocl = ot * 16 + g * 4 + r;
            float bv = bias[ocl];
            out[(size_t)rbase * 1024 + col0 + ocl] = acc[ot][0][r] + bv;
            out[(size_t)(rbase + 16) * 1024 + col0 + ocl] = acc[ot][1][r] + bv;
        }
    }
}

// ---------------- pack whh_f -> uint4 bf16 ----------------
__global__ __launch_bounds__(256) void prep_whh4_kernel(const float* __restrict__ W,
                                                        uint4* __restrict__ whh4)
{
    int idx = blockIdx.x * 256 + threadIdx.x;
    int k8 = idx >> 10, j = idx & 1023;
    const float* src = W + (size_t)j * 256 + k8 * 8;
    float4 v0 = *reinterpret_cast<const float4*>(src);
    float4 v1 = *reinterpret_cast<const float4*>(src + 4);
    uint4 w;
    w.x = f2bf_rne(v0.x) | (f2bf_rne(v0.y) << 16);
    w.y = f2bf_rne(v0.z) | (f2bf_rne(v0.w) << 16);
    w.z = f2bf_rne(v1.x) | (f2bf_rne(v1.y) << 16);
    w.w = f2bf_rne(v1.z) | (f2bf_rne(v1.w) << 16);
    whh4[(size_t)k8 * 1024 + j] = w;
}

// ---------------- fused forward LSTM (R9 proven: 199us) ----------------
// Do NOT add register-resident weights (R7/R8: 64-VGPR cap -> spills).
// Do NOT go to 2 batches/block (R10: CU starvation, 310us).
__global__ __launch_bounds__(1024) void lstm_fused_kernel(const float* __restrict__ xproj,
                                                          const uint4* __restrict__ whh4,
                                                          float* __restrict__ hfinal)
{
    int b = blockIdx.x;
    int j = threadIdx.x;
    __shared__ __align__(16) float h[256];
    __shared__ float cc[256];
    __shared__ float g[1024];
    if (j < 256) { h[j] = 0.f; cc[j] = 0.f; }
    __syncthreads();
    const uint4* wp = whh4 + j;
    for (int t = 0; t < 33; ++t) {
        float a0 = xproj[(size_t)t * 131072 + (size_t)b * 1024 + j];
        float a1 = 0.f;
#pragma unroll 8
        for (int k8 = 0; k8 < 32; ++k8) {
            uint4 w = wp[k8 << 10];
            float4 h0 = *reinterpret_cast<const float4*>(&h[k8 * 8]);
            float4 h1 = *reinterpret_cast<const float4*>(&h[k8 * 8 + 4]);
            a0 += bflo(w.x) * h0.x + bfhi(w.x) * h0.y + bflo(w.y) * h0.z + bfhi(w.y) * h0.w;
            a1 += bflo(w.z) * h1.x + bfhi(w.z) * h1.y + bflo(w.w) * h1.z + bfhi(w.w) * h1.w;
        }
        g[j] = a0 + a1;
        __syncthreads();
        if (j < 256) {
            float gi = g[j], gf = g[256 + j], gz = g[512 + j], go = g[768 + j];
            float c = fsigm(gf) * cc[j] + fsigm(gi) * ftanh(gz);
            cc[j] = c;
            h[j] = fsigm(go) * ftanh(c);
        }
        __syncthreads();
    }
    if (j < 256) hfinal[b * 256 + j] = h[j];
}

// ---------------- backward LSTM single step ----------------
__global__ __launch_bounds__(256) void lstm_bwd_tail_kernel(const float* __restrict__ gatesB,
                                                            float* __restrict__ hbLast)
{
    int b = blockIdx.x, u = threadIdx.x;
    const float* g = gatesB + (size_t)b * 1024;
    float ai = g[u], ag = g[512 + u], ao = g[768 + u];
    float c = sigm(ai) * tanhf(ag);
    hbLast[b * 256 + u] = sigm(ao) * tanhf(c);
}

// ---------------- FFN head ----------------
__global__ __launch_bounds__(256) void ffn_kernel(const float* __restrict__ hf,
                                                  const float* __restrict__ hb,
                                                  const float* __restrict__ w1,
                                                  const float* __restrict__ b1,
                                                  const float* __restrict__ w2,
                                                  const float* __restrict__ b2,
                                                  float* __restrict__ out)
{
    int b = blockIdx.x, tid = threadIdx.x;
    __shared__ float last[512];
    __shared__ float red[256];
    last[tid] = hf[b * 256 + tid];
    last[256 + tid] = hb[b * 256 + tid];
    __syncthreads();
    float a = b1[tid];
    const float* wr = w1 + (size_t)tid * 512;
    for (int k = 0; k < 512; ++k) a += last[k] * wr[k];
    red[tid] = fmaxf(a, 0.f) * w2[tid];
    __syncthreads();
    for (int s = 128; s > 0; s >>= 1) {
        if (tid < s) red[tid] += red[tid + s];
        __syncthreads();
    }
    if (tid == 0) out[b] = red[0] + b2[0];
}

extern "C" void kernel_launch(void* const* d_in, const int* in_sizes, int n_in,
                              void* d_out, int out_size, void* d_ws, size_t ws_size,
                              hipStream_t stream)
{
    (void)in_sizes; (void)n_in; (void)out_size; (void)ws_size;
    const float* x_cont = (const float*)d_in[0];
    const float* x_norm = (const float*)d_in[1];
    const float* gate_w1 = (const float*)d_in[2];
    const float* gate_b1 = (const float*)d_in[3];
    const float* gate_w2 = (const float*)d_in[4];
    const float* gate_b2 = (const float*)d_in[5];
    const float* exp_w1 = (const float*)d_in[6];
    const float* exp_b1 = (const float*)d_in[7];
    const float* exp_w2 = (const float*)d_in[8];
    const float* exp_b2 = (const float*)d_in[9];
    const float* lw1 = (const float*)d_in[10];
    const float* lb1 = (const float*)d_in[11];
    const float* lw2 = (const float*)d_in[12];
    const float* lb2 = (const float*)d_in[13];
    const float* se2_w1 = (const float*)d_in[14];
    const float* se2_w2 = (const float*)d_in[15];
    const float* lw3 = (const float*)d_in[16];
    const float* lb3 = (const float*)d_in[17];
    const float* se3_w1 = (const float*)d_in[18];
    const float* se3_w2 = (const float*)d_in[19];
    const float* wih_f = (const float*)d_in[20];
    const float* whh_f = (const float*)d_in[21];
    const float* bih_f = (const float*)d_in[22];
    const float* bhh_f = (const float*)d_in[23];
    const float* wih_b = (const float*)d_in[24];
    const float* whh_b = (const float*)d_in[25];
    const float* bih_b = (const float*)d_in[26];
    const float* bhh_b = (const float*)d_in[27];
    const float* ffn_w1 = (const float*)d_in[28];
    const float* ffn_b1 = (const float*)d_in[29];
    const float* ffn_w2 = (const float*)d_in[30];
    const float* ffn_b2 = (const float*)d_in[31];

    float* ws = (float*)d_ws;
    float* mag     = ws + F_MAG;
    float* gw      = ws + F_GW;
    int*   topi    = (int*)(ws + F_TOPI);
    unsigned short* eh1T = (unsigned short*)(ws + F_EH1);
    float* sel     = ws + F_SEL;
    float* lineFeat= ws + F_LINEF;
    unsigned short* combB = (unsigned short*)(ws + F_COMB);
    float* xproj   = ws + F_XPROJ;
    float* gatesB  = ws + F_GATESB;
    float* hfF     = ws + F_HF;
    float* hbLast  = ws + F_HBLAST;
    float* seSum2  = ws + F_SESUM2;
    float* seSc2   = ws + F_SESC2;
    float* seSum3  = ws + F_SESUM3;
    float* seSc3   = ws + F_SESC3;
    uint4* whh4    = (uint4*)(ws + F_WHHB);
    unsigned short* wkb  = (unsigned short*)(ws + F_WKB);
    unsigned short* wkb3 = (unsigned short*)(ws + F_WKB3);
    unsigned short* wihFb = (unsigned short*)(ws + F_WIHF);
    unsigned short* wihBb = (unsigned short*)(ws + F_WIHB);
    unsigned short* wkbE1 = (unsigned short*)(ws + A_WKBE1);
    unsigned short* wkbE2 = (unsigned short*)(ws + A_WKBE2);
    unsigned short* magT  = (unsigned short*)(ws + A_MAGT);
    unsigned short* p1T = (unsigned short*)(ws + F_BIGA);
    float* h2      = ws + F_BIGB;
    unsigned short* p2T = (unsigned short*)(ws + F_BIGA);
    float* h3      = ws + F_BIGB;

    hipMemsetAsync(seSum2, 0, 16384 * sizeof(float), stream);
    hipMemsetAsync(seSum3, 0, 32768 * sizeof(float), stream);

    // Expert weight prepack (lives in xproj region; dead before xproj written)
    prep_wkbE1_kernel<<<5632, 256, 0, stream>>>(exp_w1, wkbE1);
    prep_wkbE2_kernel<<<6144, 256, 0, stream>>>(exp_w2, wkbE2);

    // Frequency branch
    stft_kernel<<<B * NFR, 256, 0, stream>>>(x_cont, mag, magT);
    gate_kernel<<<B, 128, 0, stream>>>(mag, gate_w1, gate_b1, gate_w2, gate_b2, topi, gw);
    expert_conv1_mfma<<<dim3(B, 2, 4), 256, 0, stream>>>(magT, topi, wkbE1, exp_b1, eh1T);
    expert_conv2_mfma<<<dim3(B, 2, 4), 256, 0, stream>>>(eh1T, topi, wkbE2, exp_b2, sel);

    // Line branch
    prep_wkb_kernel<<<160, 256, 0, stream>>>(lw2, wkb);
    line1_kernel<<<dim3(B, 4), 256, 0, stream>>>(x_norm, lw1, lb1, p1T);
    line2_mfma_kernel<<<dim3(B, 8), 256, 0, stream>>>(p1T, wkb, lb2, h2, seSum2);
    se2_kernel<<<B, 128, 0, stream>>>(seSum2, se2_w1, se2_w2, seSc2);
    pool2t_kernel<<<B, 256, 0, stream>>>(h2, seSc2, p2T);
    prep_wkb3_kernel<<<384, 256, 0, stream>>>(lw3, wkb3);
    line3_mfma_kernel<<<dim3(B, 2, 2), 256, 0, stream>>>(p2T, wkb3, lb3, h3, seSum3);
    se3_kernel<<<B, 256, 0, stream>>>(seSum3, se3_w1, se3_w2, seSc3);
    pool3_kernel<<<2048, 256, 0, stream>>>(h3, seSc3, lineFeat);

    // Fuse features -> comb bf16
    comb_kernel<<<2048, 256, 0, stream>>>(sel, gw, lineFeat, combB);

    // Pack LSTM input-projection weights to bf16
    pack_bf16_kernel<<<512, 256, 0, stream>>>(wih_f, wihFb, 1024 * 512);
    pack_bf16_kernel<<<512, 256, 0, stream>>>(wih_b, wihBb, 1024 * 512);

    // LSTM input projections via MFMA + backward-step gates
    gemm_mfma_kernel<<<dim3(33, 8), 256, 0, stream>>>(combB, wihFb, bih_f, bhh_f, xproj);
    gemm_mfma_kernel<<<dim3(1, 8), 256, 0, stream>>>(combB + (size_t)4096 * 512, wihBb, bih_b, bhh_b, gatesB);
    lstm_bwd_tail_kernel<<<B, 256, 0, stream>>>(gatesB, hbLast);

    // Forward LSTM recurrence (R9 proven streaming structure)
    prep_whh4_kernel<<<128, 256, 0, stream>>>(whh_f, whh4);
    lstm_fused_kernel<<<B, 1024, 0, stream>>>(xproj, whh4, hfF);

    // Head
    ffn_kernel<<<B, 256, 0, stream>>>(hfF, hbLast, ffn_w1, ffn_b1, ffn_w2, ffn_b2, (float*)d_out);
}

// Round 13
// 562.385 us; speedup vs baseline: 1.3551x; 1.0521x over previous
//
#include <hip/hip_runtime.h>
#include <math.h>

namespace {
constexpr int B = 128;
constexpr int L = 4096;
constexpr int NBIN = 129;
constexpr int NFR = 33;

// workspace offsets (in floats)
constexpr size_t F_MAG    = 0;                       // B*129*33 = 544896
constexpr size_t F_GW     = F_MAG + 544896;          // 256
constexpr size_t F_TOPI   = F_GW + 256;              // 256 (ints)
constexpr size_t F_EH1    = F_TOPI + 256;            // eh1T bf16
constexpr size_t F_SEL    = F_EH1 + 2162688;         // 2162688
constexpr size_t F_LINEF  = F_SEL + 2162688;         // 2097152
constexpr size_t F_COMB   = F_LINEF + 2097152;       // bf16 comb
constexpr size_t F_XPROJ  = F_COMB + 2162688;        // 4325376 (early: wkbE1/wkbE2/magT; late: xproj)
constexpr size_t F_GATESB = F_XPROJ + 4325376;
constexpr size_t F_HF     = F_GATESB + 131072;
constexpr size_t F_HBLAST = F_HF + 32768;            // (unused now)
constexpr size_t F_SESUM2 = F_HBLAST + 32768;
constexpr size_t F_SESC2  = F_SESUM2 + 16384;        // (unused now)
constexpr size_t F_SESUM3 = F_SESC2 + 16384;
constexpr size_t F_SESC3  = F_SESUM3 + 32768;        // (unused now)
constexpr size_t F_WHHB   = F_SESC3 + 32768;         // 131072
constexpr size_t F_WKB    = F_WHHB + 131072;         // 20480
constexpr size_t F_WKB3   = F_WKB + 20480;           // 49152
constexpr size_t F_WIHF   = F_WKB3 + 49152;          // 262144
constexpr size_t F_WIHB   = F_WIHF + 262144;         // 262144
constexpr size_t F_BIGA   = F_WIHB + 262144;         // 8388608
constexpr size_t F_BIGB   = F_BIGA + 8388608;        // 16777216
// aliases inside F_XPROJ region (dead before xproj written):
constexpr size_t A_WKBE1  = F_XPROJ;                 // 8*256*704 ush = 720896 floats
constexpr size_t A_WKBE2  = F_XPROJ + 720896;        // 8*256*768 ush = 786432 floats
constexpr size_t A_MAGT   = F_XPROJ + 1507328;       // 128*33*136 ush

// prep_all block ranges (all exact multiples of 256 threads)
constexpr int PB_E1   = 5632;            // wkbE1: 1441792 elems
constexpr int PB_E2   = PB_E1 + 6144;    // wkbE2: 1572864
constexpr int PB_WKB  = PB_E2 + 160;     // wkb: 40960
constexpr int PB_WKB3 = PB_WKB + 384;    // wkb3: 98304
constexpr int PB_WF   = PB_WKB3 + 512;   // wihF pack: 524288 f32
constexpr int PB_WB   = PB_WF + 512;     // wihB pack
constexpr int PB_WHH  = PB_WB + 128;     // whh4: 32768 idx
constexpr int PB_Z2   = PB_WHH + 64;     // zero seSum2: 16384
constexpr int PB_Z3   = PB_Z2 + 128;     // zero seSum3: 32768
}

typedef __attribute__((ext_vector_type(8))) short bf16x8;
typedef __attribute__((ext_vector_type(4))) float f32x4;

__device__ __forceinline__ float sigm(float x) { return 1.0f / (1.0f + expf(-x)); }
__device__ __forceinline__ float fsigm(float x) { return 1.0f / (1.0f + __expf(-x)); }
__device__ __forceinline__ float ftanh(float x) { return 1.0f - 2.0f / (__expf(2.0f * x) + 1.0f); }

__device__ __forceinline__ unsigned int f2bf_rne(float f) {
    unsigned int u = __float_as_uint(f);
    return (u + 0x7FFFu + ((u >> 16) & 1u)) >> 16;
}
__device__ __forceinline__ float bflo(unsigned int u) { return __uint_as_float(u << 16); }
__device__ __forceinline__ float bfhi(unsigned int u) { return __uint_as_float(u & 0xFFFF0000u); }
__device__ __forceinline__ float bf2f(unsigned short s) { return __uint_as_float(((unsigned int)s) << 16); }

// ---------------- mega-prep: all weight packs + seSum zeroing in ONE launch ----------------
__global__ __launch_bounds__(256) void prep_all_kernel(const float* __restrict__ exp_w1,
                                                       const float* __restrict__ exp_w2,
                                                       const float* __restrict__ lw2,
                                                       const float* __restrict__ lw3,
                                                       const float* __restrict__ wih_f,
                                                       const float* __restrict__ wih_b,
                                                       const float* __restrict__ whh_f,
                                                       unsigned short* __restrict__ wkbE1,
                                                       unsigned short* __restrict__ wkbE2,
                                                       unsigned short* __restrict__ wkb,
                                                       unsigned short* __restrict__ wkb3,
                                                       unsigned short* __restrict__ wihFb,
                                                       unsigned short* __restrict__ wihBb,
                                                       uint4* __restrict__ whh4,
                                                       float* __restrict__ seSum2,
                                                       float* __restrict__ seSum3)
{
    int bid = blockIdx.x, tid = threadIdx.x;
    if (bid < PB_E1) {
        int idx = bid * 256 + tid;
        int eo = idx / 704, K = idx % 704;
        int k = K / 136, ic = K - k * 136;
        float v = (k < 5 && ic < 129) ? exp_w1[((size_t)eo * 129 + ic) * 5 + k] : 0.f;
        wkbE1[idx] = (unsigned short)f2bf_rne(v);
    } else if (bid < PB_E2) {
        int idx = (bid - PB_E1) * 256 + tid;
        int eo = idx / 768, K = idx % 768;
        int k = K >> 8, ic = K & 255;
        wkbE2[idx] = (unsigned short)f2bf_rne(exp_w2[((size_t)eo * 256 + ic) * 3 + k]);
    } else if (bid < PB_WKB) {
        int idx = (bid - PB_E2) * 256 + tid;
        int oc = idx / 320, K = idx % 320;
        int k = K >> 6, ic = K & 63;
        wkb[idx] = (unsigned short)f2bf_rne(lw2[oc * 320 + ic * 5 + k]);
    } else if (bid < PB_WKB3) {
        int idx = (bid - PB_WKB) * 256 + tid;
        int oc = idx / 384, K = idx % 384;
        int k = K >> 7, ic = K & 127;
        wkb3[idx] = (unsigned short)f2bf_rne(lw3[oc * 384 + ic * 3 + k]);
    } else if (bid < PB_WF) {
        int i = ((bid - PB_WKB3) * 256 + tid) * 4;
        float4 v = *reinterpret_cast<const float4*>(wih_f + i);
        uint2 w;
        w.x = f2bf_rne(v.x) | (f2bf_rne(v.y) << 16);
        w.y = f2bf_rne(v.z) | (f2bf_rne(v.w) << 16);
        *reinterpret_cast<uint2*>(wihFb + i) = w;
    } else if (bid < PB_WB) {
        int i = ((bid - PB_WF) * 256 + tid) * 4;
        float4 v = *reinterpret_cast<const float4*>(wih_b + i);
        uint2 w;
        w.x = f2bf_rne(v.x) | (f2bf_rne(v.y) << 16);
        w.y = f2bf_rne(v.z) | (f2bf_rne(v.w) << 16);
        *reinterpret_cast<uint2*>(wihBb + i) = w;
    } else if (bid < PB_WHH) {
        int idx = (bid - PB_WB) * 256 + tid;
        int k8 = idx >> 10, j = idx & 1023;
        const float* src = whh_f + (size_t)j * 256 + k8 * 8;
        float4 v0 = *reinterpret_cast<const float4*>(src);
        float4 v1 = *reinterpret_cast<const float4*>(src + 4);
        uint4 w;
        w.x = f2bf_rne(v0.x) | (f2bf_rne(v0.y) << 16);
        w.y = f2bf_rne(v0.z) | (f2bf_rne(v0.w) << 16);
        w.z = f2bf_rne(v1.x) | (f2bf_rne(v1.y) << 16);
        w.w = f2bf_rne(v1.z) | (f2bf_rne(v1.w) << 16);
        whh4[(size_t)k8 * 1024 + j] = w;
    } else if (bid < PB_Z2) {
        seSum2[(bid - PB_WHH) * 256 + tid] = 0.f;
    } else {
        seSum3[(bid - PB_Z2) * 256 + tid] = 0.f;
    }
}

// ---------------- STFT: table DFT; writes mag f32 + magT bf16 ----------------
__global__ __launch_bounds__(256) void stft_kernel(const float* __restrict__ x,
                                                   float* __restrict__ mag,
                                                   unsigned short* __restrict__ magT)
{
    int bf = blockIdx.x;            // b*33 + f
    int b = bf / NFR, f = bf % NFR;
    int tid = threadIdx.x;
    __shared__ float tbl[256];
    __shared__ float fx[256];
    tbl[tid] = cosf(6.28318530717958647692f * (float)tid / 256.0f);
    __syncthreads();
    {
        int j = f * 128 + tid - 128;
        if (j < 0) j = -j;
        else if (j >= L) j = 2 * L - 2 - j;
        float win = 0.5f * (1.0f - tbl[tid]);
        fx[tid] = x[(size_t)b * L + j] * win;
    }
    __syncthreads();
    if (tid < NBIN) {
        float re = 0.f, im = 0.f;
        int m = 0;
        for (int n = 0; n < 256; ++n) {
            float v = fx[n];
            re += v * tbl[m];
            im += v * tbl[(m + 192) & 255];
            m = (m + tid) & 255;
        }
        float val = sqrtf(re * re + im * im);
        mag[((size_t)b * NBIN + tid) * NFR + f] = val;
        magT[((size_t)b * NFR + f) * 136 + tid] = (unsigned short)f2bf_rne(val);
    } else if (tid < 136) {
        magT[((size_t)b * NFR + f) * 136 + tid] = 0;
    }
}

// ---------------- pooled mean + gate MLP + top2 ----------------
__global__ __launch_bounds__(128) void gate_kernel(const float* __restrict__ mag,
                                                   const float* __restrict__ w1,
                                                   const float* __restrict__ b1,
                                                   const float* __restrict__ w2,
                                                   const float* __restrict__ b2,
                                                   int* __restrict__ topi,
                                                   float* __restrict__ gw)
{
    int b = blockIdx.x, tid = threadIdx.x;
    __shared__ float pooled[NBIN];
    __shared__ float h1[128];
    __shared__ float lg[8];
    for (int k = tid; k < NBIN; k += 128) {
        const float* mp = mag + ((size_t)b * NBIN + k) * NFR;
        float s = 0.f;
        for (int f = 0; f < NFR; ++f) s += mp[f];
        pooled[k] = s * (1.0f / 33.0f);
    }
    __syncthreads();
    {
        float acc = b1[tid];
        const float* wr = w1 + tid * NBIN;
        for (int k = 0; k < NBIN; ++k) acc += pooled[k] * wr[k];
        h1[tid] = fmaxf(acc, 0.f);
    }
    __syncthreads();
    if (tid < 8) {
        float a = b2[tid];
        const float* w = w2 + tid * 128;
        for (int j = 0; j < 128; ++j) a += h1[j] * w[j];
        lg[tid] = a;
    }
    __syncthreads();
    if (tid == 0) {
        int i0 = 0; float v0 = lg[0];
        for (int e = 1; e < 8; ++e) if (lg[e] > v0) { v0 = lg[e]; i0 = e; }
        int i1 = -1; float v1 = -3.0e38f;
        for (int e = 0; e < 8; ++e) { if (e == i0) continue; if (lg[e] > v1) { v1 = lg[e]; i1 = e; } }
        float m = fmaxf(v0, v1);
        float e0 = expf(v0 - m), e1 = expf(v1 - m);
        float inv = 1.0f / (e0 + e1);
        topi[b * 2 + 0] = i0; topi[b * 2 + 1] = i1;
        gw[b * 2 + 0] = e0 * inv; gw[b * 2 + 1] = e1 * inv;
    }
}

// ---------------- expert conv1 via MFMA (verified R12) ----------------
__global__ __launch_bounds__(256) void expert_conv1_mfma(const unsigned short* __restrict__ magT,
                                                         const int* __restrict__ topi,
                                                         const unsigned short* __restrict__ wkbE1,
                                                         const float* __restrict__ Bb,
                                                         unsigned short* __restrict__ eh1T)
{
    int b = blockIdx.x, slot = blockIdx.y, ocq = blockIdx.z;
    int e = topi[b * 2 + slot];
    __shared__ __align__(16) unsigned short wl[64 * 704];
    __shared__ __align__(16) unsigned short inT[37 * 136];
    __shared__ float bias[64];
    int tid = threadIdx.x;
    for (int idx = tid; idx < 64 * 88; idx += 256) {
        int oc = idx / 88, ch = idx % 88;
        int swz = (ch & ~7) | ((ch & 7) ^ (oc & 7));
        *reinterpret_cast<uint4*>(&wl[oc * 704 + swz * 8]) =
            *reinterpret_cast<const uint4*>(&wkbE1[((size_t)(e * 256 + ocq * 64 + oc)) * 704 + ch * 8]);
    }
    for (int idx = tid; idx < 37 * 17; idx += 256) {
        int j = idx / 17, ch = idx % 17;
        int tp = j - 2;
        uint4 v = make_uint4(0u, 0u, 0u, 0u);
        if (tp >= 0 && tp < 33)
            v = *reinterpret_cast<const uint4*>(&magT[((size_t)b * NFR + tp) * 136 + ch * 8]);
        *reinterpret_cast<uint4*>(&inT[j * 136 + ch * 8]) = v;
    }
    if (tid < 64) bias[tid] = Bb[e * 256 + ocq * 64 + tid];
    __syncthreads();

    int lane = tid & 63, w = tid >> 6, l15 = lane & 15, g = lane >> 4;
    f32x4 acc[3];
#pragma unroll
    for (int n = 0; n < 3; ++n) acc[n] = (f32x4){0.f, 0.f, 0.f, 0.f};

    int row = w * 16 + l15;
    for (int ks = 0; ks < 22; ++ks) {
        int ch = ks * 4 + g;
        bf16x8 af = *reinterpret_cast<const bf16x8*>(
            &wl[row * 704 + (((ch & ~7) | ((ch & 7) ^ (row & 7)))) * 8]);
        int ce = ch > 84 ? 84 : ch;
        int k = ce / 17, icc = ce - k * 17;
#pragma unroll
        for (int n = 0; n < 3; ++n) {
            int t = n * 16 + l15;
            int j = t + k; if (j > 36) j = 36;
            bf16x8 bf = *reinterpret_cast<const bf16x8*>(&inT[j * 136 + icc * 8]);
            acc[n] = __builtin_amdgcn_mfma_f32_16x16x32_bf16(af, bf, acc[n], 0, 0, 0);
        }
    }
#pragma unroll
    for (int n = 0; n < 3; ++n) {
        int t = n * 16 + l15;
        if (t < 33) {
            float v0 = fmaxf(acc[n][0] + bias[w * 16 + g * 4 + 0], 0.f);
            float v1 = fmaxf(acc[n][1] + bias[w * 16 + g * 4 + 1], 0.f);
            float v2 = fmaxf(acc[n][2] + bias[w * 16 + g * 4 + 2], 0.f);
            float v3 = fmaxf(acc[n][3] + bias[w * 16 + g * 4 + 3], 0.f);
            uint2 pk;
            pk.x = f2bf_rne(v0) | (f2bf_rne(v1) << 16);
            pk.y = f2bf_rne(v2) | (f2bf_rne(v3) << 16);
            *reinterpret_cast<uint2*>(
                &eh1T[(((size_t)(b * 2 + slot)) * NFR + t) * 256 + ocq * 64 + w * 16 + g * 4]) = pk;
        }
    }
}

// ---------------- expert conv2 via MFMA (verified R12) ----------------
__global__ __launch_bounds__(256) void expert_conv2_mfma(const unsigned short* __restrict__ eh1T,
                                                         const int* __restrict__ topi,
                                                         const unsigned short* __restrict__ wkbE2,
                                                         const float* __restrict__ Bb,
                                                         float* __restrict__ sel)
{
    int b = blockIdx.x, slot = blockIdx.y, ocq = blockIdx.z;
    int e = topi[b * 2 + slot];
    __shared__ __align__(16) unsigned short wl[64 * 768];
    __shared__ __align__(16) unsigned short inT[35 * 256];
    __shared__ float bias[64];
    int tid = threadIdx.x;
    for (int idx = tid; idx < 64 * 96; idx += 256) {
        int oc = idx / 96, ch = idx % 96;
        int swz = (ch & ~7) | ((ch & 7) ^ (oc & 7));
        *reinterpret_cast<uint4*>(&wl[oc * 768 + swz * 8]) =
            *reinterpret_cast<const uint4*>(&wkbE2[((size_t)(e * 256 + ocq * 64 + oc)) * 768 + ch * 8]);
    }
    for (int idx = tid; idx < 35 * 32; idx += 256) {
        int j = idx / 32, ch = idx % 32;
        int tp = j - 1;
        uint4 v = make_uint4(0u, 0u, 0u, 0u);
        if (tp >= 0 && tp < 33)
            v = *reinterpret_cast<const uint4*>(&eh1T[(((size_t)(b * 2 + slot)) * NFR + tp) * 256 + ch * 8]);
        int swz = (ch & ~15) | ((ch & 15) ^ (j & 15));
        *reinterpret_cast<uint4*>(&inT[j * 256 + swz * 8]) = v;
    }
    if (tid < 64) bias[tid] = Bb[e * 256 + ocq * 64 + tid];
    __syncthreads();

    int lane = tid & 63, w = tid >> 6, l15 = lane & 15, g = lane >> 4;
    f32x4 acc[3];
#pragma unroll
    for (int n = 0; n < 3; ++n) acc[n] = (f32x4){0.f, 0.f, 0.f, 0.f};

    int row = w * 16 + l15;
    for (int ks = 0; ks < 24; ++ks) {
        int ch = ks * 4 + g;
        bf16x8 af = *reinterpret_cast<const bf16x8*>(
            &wl[row * 768 + (((ch & ~7) | ((ch & 7) ^ (row & 7)))) * 8]);
        int k = ch >> 5, icc = ch & 31;
#pragma unroll
        for (int n = 0; n < 3; ++n) {
            int t = n * 16 + l15;
            int j = t + k; if (j > 34) j = 34;
            int sz = (icc & ~15) | ((icc & 15) ^ (j & 15));
            bf16x8 bf = *reinterpret_cast<const bf16x8*>(&inT[j * 256 + sz * 8]);
            acc[n] = __builtin_amdgcn_mfma_f32_16x16x32_bf16(af, bf, acc[n], 0, 0, 0);
        }
    }
#pragma unroll
    for (int n = 0; n < 3; ++n) {
        int t = n * 16 + l15;
        if (t < 33) {
#pragma unroll
            for (int r = 0; r < 4; ++r) {
                int oc = ocq * 64 + w * 16 + g * 4 + r;
                float v = fmaxf(acc[n][r] + bias[w * 16 + g * 4 + r], 0.f);
                sel[(((size_t)b * 2 + slot) * 256 + oc) * NFR + t] = v;
            }
        }
    }
}

// ---------------- line conv1 + relu + maxpool4 -> p1T bf16 ----------------
__global__ __launch_bounds__(256) void line1_kernel(const float* __restrict__ x,
                                                    const float* __restrict__ lw1,
                                                    const float* __restrict__ lb1,
                                                    unsigned short* __restrict__ p1T)
{
    int b = blockIdx.x;
    int P0 = blockIdx.y * 256;
    __shared__ float sx[1032];
    __shared__ float w[448];
    __shared__ float bb[64];
    __shared__ unsigned short sT[256 * 65];
    int tid = threadIdx.x;
    for (int i = tid; i < 448; i += 256) w[i] = lw1[i];
    for (int i = tid; i < 64; i += 256) bb[i] = lb1[i];
    int base = 4 * P0 - 3;
    for (int i = tid; i < 1032; i += 256) {
        int g = base + i;
        sx[i] = (g >= 0 && g < L) ? x[(size_t)b * L + g] : 0.f;
    }
    __syncthreads();
    int p = tid;
    for (int oc = 0; oc < 64; ++oc) {
        const float* wr = w + oc * 7;
        float best = -3.0e38f;
#pragma unroll
        for (int q = 0; q < 4; ++q) {
            const float* s = sx + 4 * p + q;
            float v = wr[0]*s[0] + wr[1]*s[1] + wr[2]*s[2] + wr[3]*s[3] + wr[4]*s[4] + wr[5]*s[5] + wr[6]*s[6];
            best = fmaxf(best, v);
        }
        float v = fmaxf(best + bb[oc], 0.f);
        sT[p * 65 + oc] = (unsigned short)f2bf_rne(v);
    }
    __syncthreads();
    unsigned int* outw = reinterpret_cast<unsigned int*>(p1T);
    for (int i2 = tid; i2 < 256 * 32; i2 += 256) {
        int row = i2 >> 5, dw = i2 & 31;
        unsigned int lo = sT[row * 65 + dw * 2];
        unsigned int hi = sT[row * 65 + dw * 2 + 1];
        outw[((size_t)b * 1024 + P0 + row) * 32 + dw] = lo | (hi << 16);
    }
}

// ---------------- line conv2 via MFMA -> h2b bf16 ----------------
__global__ __launch_bounds__(256) void line2_mfma_kernel(const unsigned short* __restrict__ p1T,
                                                         const unsigned short* __restrict__ wkb,
                                                         const float* __restrict__ lb2,
                                                         unsigned short* __restrict__ h2b,
                                                         float* __restrict__ seSum2)
{
    int b = blockIdx.x;
    int t0 = blockIdx.y * 128;
    __shared__ __align__(16) unsigned short wl[128 * 320];
    __shared__ __align__(16) unsigned short inT[132 * 64];
    __shared__ float bias[128];
    int tid = threadIdx.x;

    for (int idx = tid; idx < 128 * 40; idx += 256) {
        int oc = idx / 40, ch = idx % 40;
        int swz = (ch & ~7) | ((ch & 7) ^ (oc & 7));
        *reinterpret_cast<uint4*>(&wl[oc * 320 + swz * 8]) =
            *reinterpret_cast<const uint4*>(&wkb[oc * 320 + ch * 8]);
    }
    for (int idx = tid; idx < 132 * 8; idx += 256) {
        int j = idx / 8, ch = idx % 8;
        int t = t0 - 2 + j;
        uint4 v = make_uint4(0u, 0u, 0u, 0u);
        if (t >= 0 && t < 1024)
            v = *reinterpret_cast<const uint4*>(&p1T[((size_t)b * 1024 + t) * 64 + ch * 8]);
        int swz = ch ^ (j & 7);
        *reinterpret_cast<uint4*>(&inT[j * 64 + swz * 8]) = v;
    }
    if (tid < 128) bias[tid] = lb2[tid];
    __syncthreads();

    int lane = tid & 63;
    int w = tid >> 6;
    int l15 = lane & 15, g = lane >> 4;

    f32x4 acc[8][2];
#pragma unroll
    for (int ot = 0; ot < 8; ++ot) {
        acc[ot][0] = (f32x4){0.f, 0.f, 0.f, 0.f};
        acc[ot][1] = (f32x4){0.f, 0.f, 0.f, 0.f};
    }

    for (int ks = 0; ks < 10; ++ks) {
        int k = ks >> 1;
        bf16x8 bf0, bf1;
        {
            int j = w * 32 + l15 + k;
            int ch = (ks & 1) * 4 + g;
            bf0 = *reinterpret_cast<const bf16x8*>(&inT[j * 64 + (ch ^ (j & 7)) * 8]);
            int j1 = j + 16;
            bf1 = *reinterpret_cast<const bf16x8*>(&inT[j1 * 64 + (ch ^ (j1 & 7)) * 8]);
        }
#pragma unroll
        for (int ot = 0; ot < 8; ++ot) {
            int row = ot * 16 + l15;
            int ch = ks * 4 + g;
            int swz = (ch & ~7) | ((ch & 7) ^ (row & 7));
            bf16x8 af = *reinterpret_cast<const bf16x8*>(&wl[row * 320 + swz * 8]);
            acc[ot][0] = __builtin_amdgcn_mfma_f32_16x16x32_bf16(af, bf0, acc[ot][0], 0, 0, 0);
            acc[ot][1] = __builtin_amdgcn_mfma_f32_16x16x32_bf16(af, bf1, acc[ot][1], 0, 0, 0);
        }
    }

    int tcol = t0 + w * 32 + l15;
#pragma unroll
    for (int ot = 0; ot < 8; ++ot) {
#pragma unroll
        for (int r = 0; r < 4; ++r) {
            int oc = ot * 16 + g * 4 + r;
            float bv = bias[oc];
            float v0 = fmaxf(acc[ot][0][r] + bv, 0.f);
            float v1 = fmaxf(acc[ot][1][r] + bv, 0.f);
            unsigned short* hp = h2b + ((size_t)b * 128 + oc) * 1024 + tcol;
            hp[0] = (unsigned short)f2bf_rne(v0);
            hp[16] = (unsigned short)f2bf_rne(v1);
            float s = v0 + v1;
            s += __shfl_xor(s, 1);
            s += __shfl_xor(s, 2);
            s += __shfl_xor(s, 4);
            s += __shfl_xor(s, 8);
            if (l15 == 0) atomicAdd(&seSum2[b * 128 + oc], s);
        }
    }
}

// ---------------- pool2 + SE(folded) + transpose: p2T bf16 [b][p][ic] ----------------
__global__ __launch_bounds__(256) void pool2t_kernel(const unsigned short* __restrict__ h2b,
                                                     const float* __restrict__ seSum2,
                                                     const float* __restrict__ w1,
                                                     const float* __restrict__ w2,
                                                     unsigned short* __restrict__ p2T)
{
    int b = blockIdx.x, p = threadIdx.x;   // p in [0,256)
    __shared__ float y[128];
    __shared__ float z[32];
    __shared__ float scale[128];
    __shared__ unsigned short sT[256 * 129];
    if (p < 128) y[p] = seSum2[b * 128 + p] * (1.0f / 1024.0f);
    __syncthreads();
    if (p < 32) {
        float a = 0.f;
        const float* wr = w1 + p * 128;
        for (int c = 0; c < 128; ++c) a += y[c] * wr[c];
        z[p] = fmaxf(a, 0.f);
    }
    __syncthreads();
    if (p < 128) {
        float a = 0.f;
        const float* wr = w2 + p * 32;
        for (int j = 0; j < 32; ++j) a += z[j] * wr[j];
        scale[p] = sigm(a);
    }
    __syncthreads();
    for (int c = 0; c < 128; ++c) {
        uint2 v = *reinterpret_cast<const uint2*>(&h2b[((size_t)b * 128 + c) * 1024 + 4 * p]);
        float m = fmaxf(fmaxf(bflo(v.x), bfhi(v.x)), fmaxf(bflo(v.y), bfhi(v.y))) * scale[c];
        sT[p * 129 + c] = (unsigned short)f2bf_rne(m);
    }
    __syncthreads();
    unsigned int* out = reinterpret_cast<unsigned int*>(p2T);
    for (int idx = p; idx < 256 * 64; idx += 256) {
        int row = idx >> 6, dw = idx & 63;
        unsigned int lo = sT[row * 129 + dw * 2];
        unsigned int hi = sT[row * 129 + dw * 2 + 1];
        out[((size_t)b * 256 + row) * 64 + dw] = lo | (hi << 16);
    }
}

// ---------------- line conv3 via MFMA -> h3b bf16 ----------------
__global__ __launch_bounds__(256) void line3_mfma_kernel(const unsigned short* __restrict__ p2T,
                                                         const unsigned short* __restrict__ wkb3,
                                                         const float* __restrict__ lb3,
                                                         unsigned short* __restrict__ h3b,
                                                         float* __restrict__ seSum3)
{
    int b = blockIdx.x;
    int oc0 = blockIdx.y * 128;
    int t0 = blockIdx.z * 128;
    __shared__ __align__(16) unsigned short wl[128 * 384];
    __shared__ __align__(16) unsigned short inT[130 * 128];
    __shared__ float bias[128];
    int tid = threadIdx.x;

    for (int idx = tid; idx < 128 * 48; idx += 256) {
        int oc = idx / 48, ch = idx % 48;
        int swz = (ch & ~7) | ((ch & 7) ^ (oc & 7));
        *reinterpret_cast<uint4*>(&wl[oc * 384 + swz * 8]) =
            *reinterpret_cast<const uint4*>(&wkb3[(size_t)(oc0 + oc) * 384 + ch * 8]);
    }
    for (int idx = tid; idx < 130 * 16; idx += 256) {
        int j = idx / 16, ch = idx % 16;
        int t = t0 - 1 + j;
        uint4 v = make_uint4(0u, 0u, 0u, 0u);
        if (t >= 0 && t < 256)
            v = *reinterpret_cast<const uint4*>(&p2T[((size_t)b * 256 + t) * 128 + ch * 8]);
        int swz = ch ^ (j & 15);
        *reinterpret_cast<uint4*>(&inT[j * 128 + swz * 8]) = v;
    }
    if (tid < 128) bias[tid] = lb3[oc0 + tid];
    __syncthreads();

    int lane = tid & 63;
    int w = tid >> 6;
    int l15 = lane & 15, g = lane >> 4;

    f32x4 acc[8][2];
#pragma unroll
    for (int ot = 0; ot < 8; ++ot) {
        acc[ot][0] = (f32x4){0.f, 0.f, 0.f, 0.f};
        acc[ot][1] = (f32x4){0.f, 0.f, 0.f, 0.f};
    }

    for (int ks = 0; ks < 12; ++ks) {
        int k = ks >> 2;
        int ch = (ks & 3) * 4 + g;
        bf16x8 bf0, bf1;
        {
            int j = w * 32 + l15 + k;
            bf0 = *reinterpret_cast<const bf16x8*>(&inT[j * 128 + (ch ^ (j & 15)) * 8]);
            int j1 = j + 16;
            bf1 = *reinterpret_cast<const bf16x8*>(&inT[j1 * 128 + (ch ^ (j1 & 15)) * 8]);
        }
#pragma unroll
        for (int ot = 0; ot < 8; ++ot) {
            int row = ot * 16 + l15;
            int wch = ks * 4 + g;
            int swz = (wch & ~7) | ((wch & 7) ^ (row & 7));
            bf16x8 af = *reinterpret_cast<const bf16x8*>(&wl[row * 384 + swz * 8]);
            acc[ot][0] = __builtin_amdgcn_mfma_f32_16x16x32_bf16(af, bf0, acc[ot][0], 0, 0, 0);
            acc[ot][1] = __builtin_amdgcn_mfma_f32_16x16x32_bf16(af, bf1, acc[ot][1], 0, 0, 0);
        }
    }

    int tcol = t0 + w * 32 + l15;
#pragma unroll
    for (int ot = 0; ot < 8; ++ot) {
#pragma unroll
        for (int r = 0; r < 4; ++r) {
            int ocl = ot * 16 + g * 4 + r;
            int oc = oc0 + ocl;
            float bv = bias[ocl];
            float v0 = fmaxf(acc[ot][0][r] + bv, 0.f);
            float v1 = fmaxf(acc[ot][1][r] + bv, 0.f);
            unsigned short* hp = h3b + ((size_t)b * 256 + oc) * 256 + tcol;
            hp[0] = (unsigned short)f2bf_rne(v0);
            hp[16] = (unsigned short)f2bf_rne(v1);
            float s = v0 + v1;
            s += __shfl_xor(s, 1);
            s += __shfl_xor(s, 2);
            s += __shfl_xor(s, 4);
            s += __shfl_xor(s, 8);
            if (l15 == 0) atomicAdd(&seSum3[b * 256 + oc], s);
        }
    }
}

// ---------------- pool3 + SE(folded): lineFeat = scale * maxpool4(h3b) ----------------
__global__ __launch_bounds__(256) void pool3_kernel(const unsigned short* __restrict__ h3b,
                                                    const float* __restrict__ seSum3,
                                                    const float* __restrict__ w1,
                                                    const float* __restrict__ w2,
                                                    float* __restrict__ lineFeat)
{
    int b = blockIdx.x, tid = threadIdx.x;
    __shared__ float y[256];
    __shared__ float z[64];
    __shared__ float scale[256];
    y[tid] = seSum3[b * 256 + tid] * (1.0f / 256.0f);
    __syncthreads();
    if (tid < 64) {
        float a = 0.f;
        const float* wr = w1 + tid * 256;
        for (int c = 0; c < 256; ++c) a += y[c] * wr[c];
        z[tid] = fmaxf(a, 0.f);
    }
    __syncthreads();
    {
        float a = 0.f;
        const float* wr = w2 + tid * 64;
        for (int j = 0; j < 64; ++j) a += z[j] * wr[j];
        scale[tid] = sigm(a);
    }
    __syncthreads();
    for (int idx = tid; idx < 256 * 64; idx += 256) {
        int c = idx >> 6, p = idx & 63;
        uint2 v = *reinterpret_cast<const uint2*>(&h3b[(((size_t)b * 256 + c) * 256) + 4 * p]);
        float m = fmaxf(fmaxf(bflo(v.x), bfhi(v.x)), fmaxf(bflo(v.y), bfhi(v.y)));
        lineFeat[((size_t)b * 256 + c) * 64 + p] = m * scale[c];
    }
}

// ---------------- build comb bf16 ----------------
__global__ __launch_bounds__(256) void comb_kernel(const float* __restrict__ sel,
                                                   const float* __restrict__ gw,
                                                   const float* __restrict__ lineFeat,
                                                   unsigned short* __restrict__ combB)
{
    const int total = 33 * 128 * 512;
    for (int idx = blockIdx.x * 256 + threadIdx.x; idx < total; idx += gridDim.x * 256) {
        int c = idx & 511;
        int r = idx >> 9;
        int b = r & 127;
        int t = r >> 7;
        float v;
        if (c < 256) {
            float g0 = gw[b * 2 + 0], g1 = gw[b * 2 + 1];
            v = g0 * sel[(((size_t)b * 2 + 0) * 256 + c) * NFR + t]
              + g1 * sel[(((size_t)b * 2 + 1) * 256 + c) * NFR + t];
        } else {
            int cc = c - 256;
            float xc = ((float)t + 0.5f) * (64.0f / 33.0f) - 0.5f;
            xc = fminf(fmaxf(xc, 0.0f), 63.0f);
            int lo = (int)floorf(xc);
            int hi = lo + 1; if (hi > 63) hi = 63;
            float w = xc - (float)lo;
            const float* lp = lineFeat + ((size_t)b * 256 + cc) * 64;
            v = lp[lo] * (1.0f - w) + lp[hi] * w;
        }
        combB[idx] = (unsigned short)f2bf_rne(v);
    }
}

// ---------------- MFMA GEMM (verified R10) ----------------
__global__ __launch_bounds__(256) void gemm_mfma_kernel(const unsigned short* __restrict__ A,
                                                        const unsigned short* __restrict__ W,
                                                        const float* __restrict__ b1,
                                                        const float* __restrict__ b2,
                                                        float* __restrict__ out)
{
    int row0 = blockIdx.x * 128;
    int col0 = blockIdx.y * 128;
    __shared__ __align__(16) unsigned short As[128 * 64];
    __shared__ __align__(16) unsigned short Bs[128 * 64];
    __shared__ float bias[128];
    int tid = threadIdx.x;
    if (tid < 128) bias[tid] = b1[col0 + tid] + b2[col0 + tid];
    int lane = tid & 63, w = tid >> 6, l15 = lane & 15, g = lane >> 4;

    f32x4 acc[8][2];
#pragma unroll
    for (int ot = 0; ot < 8; ++ot) {
        acc[ot][0] = (f32x4){0.f, 0.f, 0.f, 0.f};
        acc[ot][1] = (f32x4){0.f, 0.f, 0.f, 0.f};
    }

    for (int kc = 0; kc < 8; ++kc) {
        __syncthreads();
        for (int idx = tid; idx < 1024; idx += 256) {
            int r = idx >> 3, ch = idx & 7;
            int swz = ch ^ (r & 7);
            *reinterpret_cast<uint4*>(&As[r * 64 + swz * 8]) =
                *reinterpret_cast<const uint4*>(&A[(size_t)(row0 + r) * 512 + kc * 64 + ch * 8]);
            *reinterpret_cast<uint4*>(&Bs[r * 64 + swz * 8]) =
                *reinterpret_cast<const uint4*>(&W[(size_t)(col0 + r) * 512 + kc * 64 + ch * 8]);
        }
        __syncthreads();
#pragma unroll
        for (int ks = 0; ks < 2; ++ks) {
            int ch = ks * 4 + g;
            int j = w * 32 + l15;
            bf16x8 bf0 = *reinterpret_cast<const bf16x8*>(&As[j * 64 + (ch ^ (j & 7)) * 8]);
            int j1 = j + 16;
            bf16x8 bf1 = *reinterpret_cast<const bf16x8*>(&As[j1 * 64 + (ch ^ (j1 & 7)) * 8]);
#pragma unroll
            for (int ot = 0; ot < 8; ++ot) {
                int row = ot * 16 + l15;
                bf16x8 af = *reinterpret_cast<const bf16x8*>(&Bs[row * 64 + (ch ^ (row & 7)) * 8]);
                acc[ot][0] = __builtin_amdgcn_mfma_f32_16x16x32_bf16(af, bf0, acc[ot][0], 0, 0, 0);
                acc[ot][1] = __builtin_amdgcn_mfma_f32_16x16x32_bf16(af, bf1, acc[ot][1], 0, 0, 0);
            }
        }
    }

    int rbase = row0 + w * 32 + l15;
#pragma unroll
    for (int ot = 0; ot < 8; ++ot) {
#pragma unroll
        for (int r = 0; r < 4; ++r) {
            int ocl = ot * 16 + g * 4 + r;
            float bv = bias[ocl];
            out[(size_t)rbase * 1024 + col0 + ocl] = acc[ot][0][r] + bv;
            out[(size_t)(rbase + 16) * 1024 + col0 + ocl] = acc[ot][1][r] + bv;
        }
    }
}

// ---------------- fused forward LSTM (R9 proven: 199us) ----------------
// Do NOT add register-resident weights (R7/R8: 64-VGPR cap -> spills, 1 GB scratch).
// Do NOT go to 2 batches/block (R10: CU starvation, 310us).
__global__ __launch_bounds__(1024) void lstm_fused_kernel(const float* __restrict__ xproj,
                                                          const uint4* __restrict__ whh4,
                                                          float* __restrict__ hfinal)
{
    int b = blockIdx.x;
    int j = threadIdx.x;
    __shared__ __align__(16) float h[256];
    __shared__ float cc[256];
    __shared__ float g[1024];
    if (j < 256) { h[j] = 0.f; cc[j] = 0.f; }
    __syncthreads();
    const uint4* wp = whh4 + j;
    for (int t = 0; t < 33; ++t) {
        float a0 = xproj[(size_t)t * 131072 + (size_t)b * 1024 + j];
        float a1 = 0.f;
#pragma unroll 8
        for (int k8 = 0; k8 < 32; ++k8) {
            uint4 w = wp[k8 << 10];
            float4 h0 = *reinterpret_cast<const float4*>(&h[k8 * 8]);
            float4 h1 = *reinterpret_cast<const float4*>(&h[k8 * 8 + 4]);
            a0 += bflo(w.x) * h0.x + bfhi(w.x) * h0.y + bflo(w.y) * h0.z + bfhi(w.y) * h0.w;
            a1 += bflo(w.z) * h1.x + bfhi(w.z) * h1.y + bflo(w.w) * h1.z + bfhi(w.w) * h1.w;
        }
        g[j] = a0 + a1;
        __syncthreads();
        if (j < 256) {
            float gi = g[j], gf = g[256 + j], gz = g[512 + j], go = g[768 + j];
            float c = fsigm(gf) * cc[j] + fsigm(gi) * ftanh(gz);
            cc[j] = c;
            h[j] = fsigm(go) * ftanh(c);
        }
        __syncthreads();
    }
    if (j < 256) hfinal[b * 256 + j] = h[j];
}

// ---------------- FFN head (+ folded backward-LSTM single step) ----------------
__global__ __launch_bounds__(256) void ffn_kernel(const float* __restrict__ hf,
                                                  const float* __restrict__ gatesB,
                                                  const float* __restrict__ w1,
                                                  const float* __restrict__ b1,
                                                  const float* __restrict__ w2,
                                                  const float* __restrict__ b2,
                                                  float* __restrict__ out)
{
    int b = blockIdx.x, tid = threadIdx.x;
    __shared__ float last[512];
    __shared__ float red[256];
    last[tid] = hf[b * 256 + tid];
    {
        const float* g = gatesB + (size_t)b * 1024;
        float ai = g[tid], ag = g[512 + tid], ao = g[768 + tid];
        float c = sigm(ai) * tanhf(ag);
        last[256 + tid] = sigm(ao) * tanhf(c);
    }
    __syncthreads();
    float a = b1[tid];
    const float* wr = w1 + (size_t)tid * 512;
    for (int k = 0; k < 512; ++k) a += last[k] * wr[k];
    red[tid] = fmaxf(a, 0.f) * w2[tid];
    __syncthreads();
    for (int s = 128; s > 0; s >>= 1) {
        if (tid < s) red[tid] += red[tid + s];
        __syncthreads();
    }
    if (tid == 0) out[b] = red[0] + b2[0];
}

extern "C" void kernel_launch(void* const* d_in, const int* in_sizes, int n_in,
                              void* d_out, int out_size, void* d_ws, size_t ws_size,
                              hipStream_t stream)
{
    (void)in_sizes; (void)n_in; (void)out_size; (void)ws_size;
    const float* x_cont = (const float*)d_in[0];
    const float* x_norm = (const float*)d_in[1];
    const float* gate_w1 = (const float*)d_in[2];
    const float* gate_b1 = (const float*)d_in[3];
    const float* gate_w2 = (const float*)d_in[4];
    const float* gate_b2 = (const float*)d_in[5];
    const float* exp_w1 = (const float*)d_in[6];
    const float* exp_b1 = (const float*)d_in[7];
    const float* exp_w2 = (const float*)d_in[8];
    const float* exp_b2 = (const float*)d_in[9];
    const float* lw1 = (const float*)d_in[10];
    const float* lb1 = (const float*)d_in[11];
    const float* lw2 = (const float*)d_in[12];
    const float* lb2 = (const float*)d_in[13];
    const float* se2_w1 = (const float*)d_in[14];
    const float* se2_w2 = (const float*)d_in[15];
    const float* lw3 = (const float*)d_in[16];
    const float* lb3 = (const float*)d_in[17];
    const float* se3_w1 = (const float*)d_in[18];
    const float* se3_w2 = (const float*)d_in[19];
    const float* wih_f = (const float*)d_in[20];
    const float* whh_f = (const float*)d_in[21];
    const float* bih_f = (const float*)d_in[22];
    const float* bhh_f = (const float*)d_in[23];
    const float* wih_b = (const float*)d_in[24];
    const float* whh_b = (const float*)d_in[25];
    const float* bih_b = (const float*)d_in[26];
    const float* bhh_b = (const float*)d_in[27];
    const float* ffn_w1 = (const float*)d_in[28];
    const float* ffn_b1 = (const float*)d_in[29];
    const float* ffn_w2 = (const float*)d_in[30];
    const float* ffn_b2 = (const float*)d_in[31];

    float* ws = (float*)d_ws;
    float* mag     = ws + F_MAG;
    float* gw      = ws + F_GW;
    int*   topi    = (int*)(ws + F_TOPI);
    unsigned short* eh1T = (unsigned short*)(ws + F_EH1);
    float* sel     = ws + F_SEL;
    float* lineFeat= ws + F_LINEF;
    unsigned short* combB = (unsigned short*)(ws + F_COMB);
    float* xproj   = ws + F_XPROJ;
    float* gatesB  = ws + F_GATESB;
    float* hfF     = ws + F_HF;
    float* seSum2  = ws + F_SESUM2;
    float* seSum3  = ws + F_SESUM3;
    uint4* whh4    = (uint4*)(ws + F_WHHB);
    unsigned short* wkb  = (unsigned short*)(ws + F_WKB);
    unsigned short* wkb3 = (unsigned short*)(ws + F_WKB3);
    unsigned short* wihFb = (unsigned short*)(ws + F_WIHF);
    unsigned short* wihBb = (unsigned short*)(ws + F_WIHB);
    unsigned short* wkbE1 = (unsigned short*)(ws + A_WKBE1);
    unsigned short* wkbE2 = (unsigned short*)(ws + A_WKBE2);
    unsigned short* magT  = (unsigned short*)(ws + A_MAGT);
    unsigned short* p1T = (unsigned short*)(ws + F_BIGA);
    unsigned short* h2b = (unsigned short*)(ws + F_BIGB);
    unsigned short* p2T = (unsigned short*)(ws + F_BIGA);   // reuse after p1T dead
    unsigned short* h3b = (unsigned short*)(ws + F_BIGB);   // reuse after h2b dead

    // One mega-prep launch: all weight packs + seSum zeroing (replaces 7 kernels + 2 memsets)
    prep_all_kernel<<<PB_Z3, 256, 0, stream>>>(exp_w1, exp_w2, lw2, lw3, wih_f, wih_b, whh_f,
                                               wkbE1, wkbE2, wkb, wkb3, wihFb, wihBb, whh4,
                                               seSum2, seSum3);

    // Frequency branch
    stft_kernel<<<B * NFR, 256, 0, stream>>>(x_cont, mag, magT);
    gate_kernel<<<B, 128, 0, stream>>>(mag, gate_w1, gate_b1, gate_w2, gate_b2, topi, gw);
    expert_conv1_mfma<<<dim3(B, 2, 4), 256, 0, stream>>>(magT, topi, wkbE1, exp_b1, eh1T);
    expert_conv2_mfma<<<dim3(B, 2, 4), 256, 0, stream>>>(eh1T, topi, wkbE2, exp_b2, sel);

    // Line branch
    line1_kernel<<<dim3(B, 4), 256, 0, stream>>>(x_norm, lw1, lb1, p1T);
    line2_mfma_kernel<<<dim3(B, 8), 256, 0, stream>>>(p1T, wkb, lb2, h2b, seSum2);
    pool2t_kernel<<<B, 256, 0, stream>>>(h2b, seSum2, se2_w1, se2_w2, p2T);
    line3_mfma_kernel<<<dim3(B, 2, 2), 256, 0, stream>>>(p2T, wkb3, lb3, h3b, seSum3);
    pool3_kernel<<<B, 256, 0, stream>>>(h3b, seSum3, se3_w1, se3_w2, lineFeat);

    // Fuse features -> comb bf16
    comb_kernel<<<2048, 256, 0, stream>>>(sel, gw, lineFeat, combB);

    // LSTM input projections via MFMA
    gemm_mfma_kernel<<<dim3(33, 8), 256, 0, stream>>>(combB, wihFb, bih_f, bhh_f, xproj);
    gemm_mfma_kernel<<<dim3(1, 8), 256, 0, stream>>>(combB + (size_t)4096 * 512, wihBb, bih_b, bhh_b, gatesB);

    // Forward LSTM recurrence (R9 proven streaming structure)
    lstm_fused_kernel<<<B, 1024, 0, stream>>>(xproj, whh4, hfF);

    // Head (+ folded backward tail)
    ffn_kernel<<<B, 256, 0, stream>>>(hfF, gatesB, ffn_w1, ffn_b1, ffn_w2, ffn_b2, (float*)d_out);
}